// Round 6
// baseline (252.565 us; speedup 1.0000x reference)
//
#include <hip/hip_runtime.h>
#include <stdint.h>

#define NB 4
#define NN 128
#define NP 512
#define NJ 640
#define HD 64
#define ED 32

typedef unsigned short u16;
typedef __attribute__((ext_vector_type(8))) short short8;
typedef __attribute__((ext_vector_type(4))) float f32x4;

// out element offsets (f32): upd_q[2048], upd_x[1536], tor[7168], o[32768]
#define OFF_Q 0
#define OFF_X 2048
#define OFF_T 3584
#define OFF_O 10752

__device__ __forceinline__ u16 f2bf(float f) {
  union { float f; uint32_t i; } v; v.f = f;
  uint32_t x = v.i;
  return (u16)((x + 0x7FFFu + ((x >> 16) & 1u)) >> 16);
}
__device__ __forceinline__ uint32_t pk2(float a, float b) {
  return (uint32_t)f2bf(a) | ((uint32_t)f2bf(b) << 16);
}

// feature k (0..127) -> Wm1 row, or -1 for zero-pad
__device__ __forceinline__ int w1row(int k) {
  if (k < 32) return 128 + k;          // e
  if (k < 35) return 160 + (k - 32);   // local_x
  if (k < 39) return 163 + (k - 35);   // local_q
  if (k == 39) return 167;             // d2
  if (k == 40) return 168;             // qdot
  if (k < 48) return -1;               // pad
  if (k < 112) return 64 + (k - 48);   // h_j
  return -1;                           // pad
}

// One block per (b,i). 8 waves, 5 edge-tiles of 16 each.
// F layout (bf16, 136-short rows): k0..31=e, k32..40=geo, k41..47=0,
// k48..111=h_j, k112..127=0.
// LDS union: [staging] W2/Wx1/Wx2 bf16   <->   [loop] sF + sT (disjoint in time)
__global__ void __launch_bounds__(512, 4)
egnn_fused(const float* __restrict__ q, const float* __restrict__ x,
           const float* __restrict__ h, const float* __restrict__ e,
           const float* __restrict__ pe, const float* __restrict__ pq,
           const float* __restrict__ px, const float* __restrict__ ph,
           const float* __restrict__ Wm1, const float* __restrict__ bm1,
           const float* __restrict__ Wm2, const float* __restrict__ bm2,
           const float* __restrict__ Wx1, const float* __restrict__ bx1,
           const float* __restrict__ Wx2, const float* __restrict__ bx2,
           const float* __restrict__ Wf1, const float* __restrict__ bf1,
           const float* __restrict__ Wf2, const float* __restrict__ bf2_,
           const float* __restrict__ Wq1, const float* __restrict__ bq1,
           const float* __restrict__ Wq2, const float* __restrict__ bq2,
           const float* __restrict__ Wt1, const float* __restrict__ bt1,
           const float* __restrict__ Wt2, const float* __restrict__ bt2,
           float* __restrict__ out)
{
  __shared__ u16 sW1B[64 * 136];               // W1 bf16, [n][k] (persistent)
  __shared__ __align__(16) u16 sUnion[26624];  // 53248 B shared region
  __shared__ float sDxT[8][16][4];
  __shared__ float sMsum[8][64];
  __shared__ float sDx[8][4];
  __shared__ float sHi64[64];
  __shared__ float sHiP[64];                   // Hi = h_i@Wm1[0:64]+bm1
  __shared__ float sPh3[4][64];

  const int b = blockIdx.x >> 7;
  const int i = blockIdx.x & 127;
  const int tid = threadIdx.x;
  const int wid = tid >> 6;        // 0..7
  const int lane = tid & 63;
  const int nl = lane & 15;
  const int quad = lane >> 4;
  const size_t node = (size_t)(b * NN + i);

  // staging view of the union
  u16* sW2B  = sUnion;             // 64*72
  u16* sWx1B = sUnion + 4608;      // 64*72
  u16* sWx2B = sUnion + 9216;      // 16*72
  // loop view of the union
  u16* sFw = sUnion + wid * 2176;          // 16*136 per wave
  u16* sTw = sUnion + 17408 + wid * 1152;  // 16*72 per wave

  // ---- stage weights to LDS (bf16, B-fragment-friendly [n][k]) ----
  for (int idx = tid; idx < 64 * 128; idx += 512) {
    int n = idx >> 7, k = idx & 127;
    int row = w1row(k);
    sW1B[n * 136 + k] = (row < 0) ? (u16)0 : f2bf(Wm1[(size_t)row * 64 + n]);
  }
  for (int idx = tid; idx < 64 * 64; idx += 512) {
    int n = idx >> 6, k = idx & 63;
    sW2B[n * 72 + k]  = f2bf(Wm2[(size_t)k * 64 + n]);
    sWx1B[n * 72 + k] = f2bf(Wx1[(size_t)k * 64 + n]);
  }
  for (int idx = tid; idx < 16 * 64; idx += 512) {
    int n = idx >> 6, k = idx & 63;
    sWx2B[n * 72 + k] = (n < 3) ? f2bf(Wx2[(size_t)k * 3 + n]) : (u16)0;
  }

  if (tid < 64) sHi64[tid] = h[node * HD + tid];
  if (tid >= 64 && tid < 128) {
    int col = tid - 64;
    float acc = bm1[col];
#pragma unroll 8
    for (int k = 0; k < HD; ++k) acc += h[node * HD + k] * Wm1[k * 64 + col];
    sHiP[col] = acc;
  }

  const float* qr0 = q + node * 4;
  const float qi0 = qr0[0], qi1 = qr0[1], qi2 = qr0[2], qi3 = qr0[3];
  const float* xr0 = x + node * 3;
  const float xi0 = xr0[0], xi1 = xr0[1], xi2 = xr0[2];

  __syncthreads();  // staging + sHiP ready

  // ---- small weight fragments in registers (18 short8 = 72 VGPRs) ----
  short8 W2f[4][2], Wx1f[4][2], Wx2f[2];
#pragma unroll
  for (int nt = 0; nt < 4; ++nt)
#pragma unroll
    for (int ks = 0; ks < 2; ++ks) {
      W2f[nt][ks]  = *(const short8*)&sW2B[(nt * 16 + nl) * 72 + ks * 32 + quad * 8];
      Wx1f[nt][ks] = *(const short8*)&sWx1B[(nt * 16 + nl) * 72 + ks * 32 + quad * 8];
    }
#pragma unroll
  for (int ks = 0; ks < 2; ++ks)
    Wx2f[ks] = *(const short8*)&sWx2B[nl * 72 + ks * 32 + quad * 8];

  float HiF[4], bm2F[4], bx1F[4];
#pragma unroll
  for (int nt = 0; nt < 4; ++nt) {
    HiF[nt] = sHiP[nt * 16 + nl];
    bm2F[nt] = bm2[nt * 16 + nl];
    bx1F[nt] = bx1[nt * 16 + nl];
  }
  const float bx2F = (nl < 3) ? bx2[nl] : 0.f;

  __syncthreads();  // all waves done reading staging area; union becomes sF/sT

  // zero own F tile (pad columns; live regions rewritten per tile)
  for (int idx = lane; idx < 16 * 136 / 2; idx += 64) ((uint32_t*)sFw)[idx] = 0;

  f32x4 msum[4];
#pragma unroll
  for (int nt = 0; nt < 4; ++nt) msum[nt] = (f32x4){0.f, 0.f, 0.f, 0.f};
  float dxs0 = 0.f, dxs1 = 0.f, dxs2 = 0.f;
  float nqw = 0.f, nqx = 0.f, nqy = 0.f, nqz = 0.f;

  for (int tile = wid; tile < 40; tile += 8) {
    const int jb = tile * 16;
    // ---- build F (wave-private LDS; no block barrier needed) ----
    {
      int er = lane >> 2, c = lane & 3;
      int jr = jb + er;
      const float* ebase = (jr < NN)
          ? e + ((node * NN) + jr) * ED + c * 8
          : pe + ((node * NP) + (jr - NN)) * ED + c * 8;
      float4 e0 = *(const float4*)ebase;
      float4 e1 = *(const float4*)(ebase + 4);
      uint4 pw;
      pw.x = pk2(e0.x, e0.y); pw.y = pk2(e0.z, e0.w);
      pw.z = pk2(e1.x, e1.y); pw.w = pk2(e1.z, e1.w);
      *(uint4*)&sFw[er * 136 + c * 8] = pw;

      const float* hb = (jr < NN) ? h + ((size_t)(b * NN + jr)) * HD + c * 16
                                  : ph + ((size_t)(b * NP + (jr - NN))) * HD + c * 16;
      float4 h0 = *(const float4*)hb, h1 = *(const float4*)(hb + 4);
      float4 h2 = *(const float4*)(hb + 8), h3 = *(const float4*)(hb + 12);
      uint4 pa, pb;
      pa.x = pk2(h0.x, h0.y); pa.y = pk2(h0.z, h0.w);
      pa.z = pk2(h1.x, h1.y); pa.w = pk2(h1.z, h1.w);
      pb.x = pk2(h2.x, h2.y); pb.y = pk2(h2.z, h2.w);
      pb.z = pk2(h3.x, h3.y); pb.w = pk2(h3.z, h3.w);
      *(uint4*)&sFw[er * 136 + 48 + c * 16] = pa;
      *(uint4*)&sFw[er * 136 + 56 + c * 16] = pb;

      if (lane < 16) {
        int j = jb + lane;
        const float* qr = (j < NN) ? q + ((size_t)(b * NN + j)) * 4
                                   : pq + ((size_t)(b * NP + (j - NN))) * 4;
        float4 qj = *(const float4*)qr;
        const float* xr = (j < NN) ? x + ((size_t)(b * NN + j)) * 3
                                   : px + ((size_t)(b * NP + (j - NN))) * 3;
        float xj0 = xr[0], xj1 = xr[1], xj2 = xr[2];
        float d0 = xi0 - xj0, d1 = xi1 - xj1, d2v = xi2 - xj2;
        float d2 = d0 * d0 + d1 * d1 + d2v * d2v;
        float qdot = fabsf(qi0 * qj.x + qi1 * qj.y + qi2 * qj.z + qi3 * qj.w);
        float ajw = qj.x, ajx = -qj.y, ajy = -qj.z, ajz = -qj.w;  // conj
        float t0 = 2.f * (ajy * d2v - ajz * d1);
        float t1 = 2.f * (ajz * d0 - ajx * d2v);
        float t2 = 2.f * (ajx * d1 - ajy * d0);
        float lx0 = d0 + ajw * t0 + (ajy * t2 - ajz * t1);
        float lx1 = d1 + ajw * t1 + (ajz * t0 - ajx * t2);
        float lx2 = d2v + ajw * t2 + (ajx * t1 - ajy * t0);
        float lqw = ajw * qi0 - ajx * qi1 - ajy * qi2 - ajz * qi3;
        float lqx = ajw * qi1 + ajx * qi0 + ajy * qi3 - ajz * qi2;
        float lqy = ajw * qi2 - ajx * qi3 + ajy * qi0 + ajz * qi1;
        float lqz = ajw * qi3 + ajx * qi2 - ajy * qi1 + ajz * qi0;
        float nn2 = qj.x * qj.x + qj.y * qj.y + qj.z * qj.z + qj.w * qj.w;
        float rn = 1.f / fmaxf(sqrtf(nn2), 1e-12f);
        nqw = qj.x * rn; nqx = qj.y * rn; nqy = qj.z * rn; nqz = qj.w * rn;
        uint4 g0, g1;
        g0.x = pk2(lx0, lx1); g0.y = pk2(lx2, lqw);
        g0.z = pk2(lqx, lqy); g0.w = pk2(lqz, d2);
        g1.x = pk2(qdot, 0.f); g1.y = 0; g1.z = 0; g1.w = 0;
        *(uint4*)&sFw[lane * 136 + 32] = g0;
        *(uint4*)&sFw[lane * 136 + 40] = g1;
      }
    }

    // ---- layer 1: a1 = relu(F@W1 + (Hi broadcast)); W1 B-frags from LDS ----
    f32x4 acc[4];
#pragma unroll
    for (int nt = 0; nt < 4; ++nt)
      acc[nt] = (f32x4){HiF[nt], HiF[nt], HiF[nt], HiF[nt]};
#pragma unroll
    for (int ks = 0; ks < 4; ++ks) {
      short8 af = *(const short8*)&sFw[nl * 136 + ks * 32 + quad * 8];
#pragma unroll
      for (int nt = 0; nt < 4; ++nt) {
        short8 bfr = *(const short8*)&sW1B[(nt * 16 + nl) * 136 + ks * 32 + quad * 8];
        acc[nt] = __builtin_amdgcn_mfma_f32_16x16x32_bf16(af, bfr, acc[nt], 0, 0, 0);
      }
    }
#pragma unroll
    for (int nt = 0; nt < 4; ++nt)
#pragma unroll
      for (int r = 0; r < 4; ++r)
        sTw[(quad * 4 + r) * 72 + nt * 16 + nl] = f2bf(fmaxf(acc[nt][r], 0.f));

    // ---- layer 2: m = a1@W2 + bm2, mask j==i, accumulate msum ----
#pragma unroll
    for (int nt = 0; nt < 4; ++nt)
      acc[nt] = (f32x4){bm2F[nt], bm2F[nt], bm2F[nt], bm2F[nt]};
#pragma unroll
    for (int ks = 0; ks < 2; ++ks) {
      short8 af = *(const short8*)&sTw[nl * 72 + ks * 32 + quad * 8];
#pragma unroll
      for (int nt = 0; nt < 4; ++nt)
        acc[nt] = __builtin_amdgcn_mfma_f32_16x16x32_bf16(af, W2f[nt][ks], acc[nt], 0, 0, 0);
    }
#pragma unroll
    for (int nt = 0; nt < 4; ++nt)
#pragma unroll
      for (int r = 0; r < 4; ++r) {
        int row = quad * 4 + r;
        float v = acc[nt][r];
        if (jb + row == i) v = 0.f;
        msum[nt][r] += v;
        sTw[row * 72 + nt * 16 + nl] = f2bf(v);
      }

    // ---- dx layer 1: x1 = relu(m@Wx1 + bx1) ----
#pragma unroll
    for (int nt = 0; nt < 4; ++nt)
      acc[nt] = (f32x4){bx1F[nt], bx1F[nt], bx1F[nt], bx1F[nt]};
#pragma unroll
    for (int ks = 0; ks < 2; ++ks) {
      short8 af = *(const short8*)&sTw[nl * 72 + ks * 32 + quad * 8];
#pragma unroll
      for (int nt = 0; nt < 4; ++nt)
        acc[nt] = __builtin_amdgcn_mfma_f32_16x16x32_bf16(af, Wx1f[nt][ks], acc[nt], 0, 0, 0);
    }
#pragma unroll
    for (int nt = 0; nt < 4; ++nt)
#pragma unroll
      for (int r = 0; r < 4; ++r)
        sTw[(quad * 4 + r) * 72 + nt * 16 + nl] = f2bf(fmaxf(acc[nt][r], 0.f));

    // ---- dx layer 2: dx = x1@Wx2 + bx2 (cols 0..2) ----
    f32x4 dacc = (f32x4){bx2F, bx2F, bx2F, bx2F};
#pragma unroll
    for (int ks = 0; ks < 2; ++ks) {
      short8 af = *(const short8*)&sTw[nl * 72 + ks * 32 + quad * 8];
      dacc = __builtin_amdgcn_mfma_f32_16x16x32_bf16(af, Wx2f[ks], dacc, 0, 0, 0);
    }
    if (nl < 3) {
#pragma unroll
      for (int r = 0; r < 4; ++r) sDxT[wid][quad * 4 + r][nl] = dacc[r];
    }
    // rotate by normalized q_j and accumulate (lanes 0..15; nq held from geo phase)
    if (lane < 16) {
      int j = jb + lane;
      if (j != i) {
        float dxc0 = sDxT[wid][lane][0];
        float dxc1 = sDxT[wid][lane][1];
        float dxc2 = sDxT[wid][lane][2];
        float rt0 = 2.f * (nqy * dxc2 - nqz * dxc1);
        float rt1 = 2.f * (nqz * dxc0 - nqx * dxc2);
        float rt2 = 2.f * (nqx * dxc1 - nqy * dxc0);
        dxs0 += dxc0 + nqw * rt0 + (nqy * rt2 - nqz * rt1);
        dxs1 += dxc1 + nqw * rt1 + (nqz * rt0 - nqx * rt2);
        dxs2 += dxc2 + nqw * rt2 + (nqx * rt1 - nqy * rt0);
      }
    }
  }

  // ---- per-wave reductions ----
#pragma unroll
  for (int nt = 0; nt < 4; ++nt) {
    float s = msum[nt][0] + msum[nt][1] + msum[nt][2] + msum[nt][3];
    s += __shfl_xor(s, 16);
    s += __shfl_xor(s, 32);
    if (lane < 16) sMsum[wid][nt * 16 + lane] = s;
  }
  {
    float a = dxs0, bb = dxs1, cc = dxs2;
#pragma unroll
    for (int off = 1; off < 16; off <<= 1) {
      a += __shfl_xor(a, off);
      bb += __shfl_xor(bb, off);
      cc += __shfl_xor(cc, off);
    }
    if (lane == 0) { sDx[wid][0] = a; sDx[wid][1] = bb; sDx[wid][2] = cc; }
  }
  __syncthreads();

  // ---- phase 3: per-node epilogues, one wave each (waves 4..7 idle) ----
  if (wid == 0) {
    float ms = 0.f;
#pragma unroll
    for (int w = 0; w < 8; ++w) ms += sMsum[w][lane];
    sPh3[0][lane] = ms;
    float f1a = bf1[lane], f1b = 0.f;
#pragma unroll 8
    for (int k = 0; k < 64; ++k) {
      f1a += sHi64[k] * Wf1[k * 64 + lane];
      f1b += sPh3[0][k] * Wf1[(64 + k) * 64 + lane];
    }
    float f1 = fmaxf(f1a + f1b, 0.f);
    sPh3[0][lane] = f1;
    float oacc = bf2_[lane];
#pragma unroll 8
    for (int k = 0; k < 64; ++k) oacc += sPh3[0][k] * Wf2[k * 64 + lane];
    out[OFF_O + node * 64 + lane] = oacc;
  } else if (wid == 1) {
    float ms = 0.f;
#pragma unroll
    for (int w = 0; w < 8; ++w) ms += sMsum[w][lane];
    sPh3[1][lane] = ms;
    float a = bq1[lane];
#pragma unroll 8
    for (int k = 0; k < 64; ++k) a += sPh3[1][k] * Wq1[k * 64 + lane];
    a = fmaxf(a, 0.f);
    float p0 = a * Wq2[lane * 4 + 0];
    float p1 = a * Wq2[lane * 4 + 1];
    float p2 = a * Wq2[lane * 4 + 2];
    float p3 = a * Wq2[lane * 4 + 3];
#pragma unroll
    for (int off = 32; off >= 1; off >>= 1) {
      p0 += __shfl_xor(p0, off);
      p1 += __shfl_xor(p1, off);
      p2 += __shfl_xor(p2, off);
      p3 += __shfl_xor(p3, off);
    }
    float dq0 = p0 + bq2[0], dq1 = p1 + bq2[1];
    float dq2 = p2 + bq2[2], dq3 = p3 + bq2[3];
    float n = fmaxf(sqrtf(dq0 * dq0 + dq1 * dq1 + dq2 * dq2 + dq3 * dq3), 1e-12f);
    dq0 /= n; dq1 /= n; dq2 /= n; dq3 /= n;
    float uw = qi0 * dq0 - qi1 * dq1 - qi2 * dq2 - qi3 * dq3;
    float ux = qi0 * dq1 + qi1 * dq0 + qi2 * dq3 - qi3 * dq2;
    float uy = qi0 * dq2 - qi1 * dq3 + qi2 * dq0 + qi3 * dq1;
    float uz = qi0 * dq3 + qi1 * dq2 - qi2 * dq1 + qi3 * dq0;
    float n2 = fmaxf(sqrtf(uw * uw + ux * ux + uy * uy + uz * uz), 1e-12f);
    if (lane == 0) {
      float* po = out + OFF_Q + node * 4;
      po[0] = uw / n2; po[1] = ux / n2; po[2] = uy / n2; po[3] = uz / n2;
    }
  } else if (wid == 2) {
    float ms = 0.f;
#pragma unroll
    for (int w = 0; w < 8; ++w) ms += sMsum[w][lane];
    sPh3[2][lane] = ms;
    float a = bt1[lane];
#pragma unroll 8
    for (int k = 0; k < 64; ++k) a += sPh3[2][k] * Wt1[k * 64 + lane];
    a = fmaxf(a, 0.f);
    sPh3[2][lane] = a;
    if (lane < 14) {
      float v = bt2[lane];
#pragma unroll 8
      for (int k = 0; k < 64; ++k) v += sPh3[2][k] * Wt2[k * 14 + lane];
      float pv = __shfl_xor(v, 1);
      float nrm = fmaxf(sqrtf(v * v + pv * pv), 1e-12f);
      out[OFF_T + node * 14 + lane] = v / nrm;
    }
  } else if (wid == 3) {
    if (lane < 3) {
      float xs = 0.f;
#pragma unroll
      for (int w = 0; w < 8; ++w) xs += sDx[w][lane];
      float xiv = (lane == 0) ? xi0 : (lane == 1) ? xi1 : xi2;
      out[OFF_X + node * 3 + lane] = xiv + xs / 639.0f;
    }
  }
}

extern "C" void kernel_launch(void* const* d_in, const int* in_sizes, int n_in,
                              void* d_out, int out_size, void* d_ws, size_t ws_size,
                              hipStream_t stream) {
  const float* q   = (const float*)d_in[0];
  const float* x   = (const float*)d_in[1];
  const float* h   = (const float*)d_in[3];
  const float* e   = (const float*)d_in[4];
  const float* pq  = (const float*)d_in[6];
  const float* px  = (const float*)d_in[7];
  const float* pe  = (const float*)d_in[8];
  const float* ph  = (const float*)d_in[9];
  const float* Wm1 = (const float*)d_in[11];
  const float* bm1 = (const float*)d_in[12];
  const float* Wm2 = (const float*)d_in[13];
  const float* bm2 = (const float*)d_in[14];
  const float* Wf1 = (const float*)d_in[15];
  const float* bf1 = (const float*)d_in[16];
  const float* Wf2 = (const float*)d_in[17];
  const float* bf2_ = (const float*)d_in[18];
  const float* Wx1 = (const float*)d_in[19];
  const float* bx1 = (const float*)d_in[20];
  const float* Wx2 = (const float*)d_in[21];
  const float* bx2 = (const float*)d_in[22];
  const float* Wq1 = (const float*)d_in[23];
  const float* bq1 = (const float*)d_in[24];
  const float* Wq2 = (const float*)d_in[25];
  const float* bq2 = (const float*)d_in[26];
  const float* Wt1 = (const float*)d_in[27];
  const float* bt1 = (const float*)d_in[28];
  const float* Wt2 = (const float*)d_in[29];
  const float* bt2 = (const float*)d_in[30];

  egnn_fused<<<NB * NN, 512, 0, stream>>>(
      q, x, h, e, pe, pq, px, ph,
      Wm1, bm1, Wm2, bm2, Wx1, bx1, Wx2, bx2,
      Wf1, bf1, Wf2, bf2_, Wq1, bq1, Wq2, bq2,
      Wt1, bt1, Wt2, bt2, (float*)d_out);
}

// Round 7
// 251.814 us; speedup vs baseline: 1.0030x; 1.0030x over previous
//
#include <hip/hip_runtime.h>
#include <stdint.h>

#define NB 4
#define NN 128
#define NP 512
#define NJ 640
#define HD 64
#define ED 32

typedef unsigned short u16;
typedef __attribute__((ext_vector_type(8))) short short8;
typedef __attribute__((ext_vector_type(4))) float f32x4;

// out element offsets (f32): upd_q[2048], upd_x[1536], tor[7168], o[32768]
#define OFF_Q 0
#define OFF_X 2048
#define OFF_T 3584
#define OFF_O 10752

// d_ws float offsets
#define WS_HALL 0         // 4*640*64 = 163840
#define WS_HI   163840    // 512*64   = 32768
#define WS_PM   196608    // 512*2*64 = 65536
#define WS_PDX  262144    // 512*2*4  = 4096

__device__ __forceinline__ u16 f2bf(float f) {
  union { float f; uint32_t i; } v; v.f = f;
  uint32_t x = v.i;
  return (u16)((x + 0x7FFFu + ((x >> 16) & 1u)) >> 16);
}
__device__ __forceinline__ uint32_t pk2(float a, float b) {
  return (uint32_t)f2bf(a) | ((uint32_t)f2bf(b) << 16);
}

// ---------------------------------------------------------------------------
// K1: Hall[b,j,:] = h_all[b,j]@Wm1[64:128]; Hi[node,:] = h[node]@Wm1[0:64]+bm1
// grid = 48 blocks x 256 (blocks 0..39: Hall 64 rows each; 40..47: Hi)
// ---------------------------------------------------------------------------
__global__ void __launch_bounds__(256)
k1_precompute(const float* __restrict__ h, const float* __restrict__ ph,
              const float* __restrict__ Wm1, const float* __restrict__ bm1,
              float* __restrict__ Hall, float* __restrict__ Hi)
{
  __shared__ float sW[64 * 64];
  const int blk = blockIdx.x;
  const int tid = threadIdx.x;
  const bool isHi = blk >= 40;
  const int wofs = isHi ? 0 : 64;
  for (int idx = tid; idx < 4096; idx += 256)
    sW[idx] = Wm1[(size_t)(wofs + (idx >> 6)) * 64 + (idx & 63)];
  __syncthreads();
  const int lane = tid & 63;
  const int wid = tid >> 6;
  const int base = (isHi ? (blk - 40) : blk) * 64 + wid * 16;
  for (int rt = 0; rt < 4; ++rt) {
    int r = base + rt * 4;
    const float* hr[4];
#pragma unroll
    for (int u = 0; u < 4; ++u) {
      int rr = r + u;
      if (isHi) hr[u] = h + (size_t)rr * 64;
      else {
        int bb = rr / NJ, j = rr % NJ;
        hr[u] = (j < NN) ? h + (size_t)(bb * NN + j) * 64
                         : ph + (size_t)(bb * NP + (j - NN)) * 64;
      }
    }
    float a0 = isHi ? bm1[lane] : 0.f, a1 = a0, a2 = a0, a3 = a0;
#pragma unroll 8
    for (int k = 0; k < 64; ++k) {
      float w = sW[k * 64 + lane];
      a0 += hr[0][k] * w; a1 += hr[1][k] * w;
      a2 += hr[2][k] * w; a3 += hr[3][k] * w;
    }
    float* dst = isHi ? Hi : Hall;
    dst[(size_t)(r + 0) * 64 + lane] = a0;
    dst[(size_t)(r + 1) * 64 + lane] = a1;
    dst[(size_t)(r + 2) * 64 + lane] = a2;
    dst[(size_t)(r + 3) * 64 + lane] = a3;
  }
}

// ---------------------------------------------------------------------------
// K2: edge loop. grid = 1024 (node x 2 halves), 256 threads, 4 waves x 5 tiles.
// F layout (bf16, 72-short rows): k0..31=e, k32..40=geo, k41..63=0.
// ---------------------------------------------------------------------------
__global__ void __launch_bounds__(256, 4)
k2_edges(const float* __restrict__ q, const float* __restrict__ x,
         const float* __restrict__ e, const float* __restrict__ pe,
         const float* __restrict__ pq, const float* __restrict__ px,
         const float* __restrict__ Wm1, const float* __restrict__ Wm2,
         const float* __restrict__ bm2, const float* __restrict__ Wx1,
         const float* __restrict__ bx1, const float* __restrict__ Wx2,
         const float* __restrict__ bx2,
         const float* __restrict__ Hall, const float* __restrict__ Hi,
         float* __restrict__ pm, float* __restrict__ pdx)
{
  __shared__ u16 sW1B[64 * 72];    // W1 (K=64 compact), [n][k]
  __shared__ u16 sWx1B[64 * 72];   // Wx1, [n][k]
  __shared__ u16 sF[4][16 * 72];   // per-wave feature tile
  __shared__ u16 sT[4][16 * 72];   // per-wave transform buffer
  __shared__ float sDxT[4][16][4];
  __shared__ float sMsum[4][64];
  __shared__ float sDxS[4][4];

  const int node = blockIdx.x >> 1;
  const int hb = blockIdx.x & 1;
  const int b = node >> 7;
  const int i = node & 127;
  const int tid = threadIdx.x;
  const int wid = tid >> 6;
  const int lane = tid & 63;
  const int nl = lane & 15;
  const int quad = lane >> 4;

  u16* sFw = sF[wid];
  u16* sTw = sT[wid];

  // stage W1 / Wx1 to LDS (bf16, [n][k])
  for (int idx = tid; idx < 64 * 64; idx += 256) {
    int n = idx >> 6, k = idx & 63;
    int row = (k < 32) ? (128 + k) : ((k < 41) ? (160 + (k - 32)) : -1);
    sW1B[n * 72 + k] = (row < 0) ? (u16)0 : f2bf(Wm1[(size_t)row * 64 + n]);
    sWx1B[n * 72 + k] = f2bf(Wx1[(size_t)k * 64 + n]);
  }
  // zero own F tile (pad cols 41..63 stay zero; live cols rewritten per tile)
  for (int idx = lane; idx < 16 * 72 / 2; idx += 64) ((uint32_t*)sFw)[idx] = 0;

  const float* qr0 = q + (size_t)node * 4;
  const float qi0 = qr0[0], qi1 = qr0[1], qi2 = qr0[2], qi3 = qr0[3];
  const float* xr0 = x + (size_t)node * 3;
  const float xi0 = xr0[0], xi1 = xr0[1], xi2 = xr0[2];

  // register B-frags: W2 (32 VGPR) + Wx2 (8 VGPR)
  short8 W2f[4][2], Wx2f[2];
#pragma unroll
  for (int nt = 0; nt < 4; ++nt)
#pragma unroll
    for (int ks = 0; ks < 2; ++ks) {
      short8 v;
#pragma unroll
      for (int jj = 0; jj < 8; ++jj) {
        int k = ks * 32 + quad * 8 + jj;
        v[jj] = (short)f2bf(Wm2[(size_t)k * 64 + nt * 16 + nl]);
      }
      W2f[nt][ks] = v;
    }
#pragma unroll
  for (int ks = 0; ks < 2; ++ks) {
    short8 v;
#pragma unroll
    for (int jj = 0; jj < 8; ++jj) {
      int k = ks * 32 + quad * 8 + jj;
      v[jj] = (nl < 3) ? (short)f2bf(Wx2[(size_t)k * 3 + nl]) : (short)0;
    }
    Wx2f[ks] = v;
  }

  float HiF[4], bm2F[4], bx1F[4];
#pragma unroll
  for (int nt = 0; nt < 4; ++nt) {
    HiF[nt] = Hi[(size_t)node * 64 + nt * 16 + nl];
    bm2F[nt] = bm2[nt * 16 + nl];
    bx1F[nt] = bx1[nt * 16 + nl];
  }
  const float bx2F = (nl < 3) ? bx2[nl] : 0.f;

  __syncthreads();  // W1/Wx1 staged

  f32x4 msum[4];
#pragma unroll
  for (int nt = 0; nt < 4; ++nt) msum[nt] = (f32x4){0.f, 0.f, 0.f, 0.f};
  float dxs0 = 0.f, dxs1 = 0.f, dxs2 = 0.f;
  float nqw = 0.f, nqx = 0.f, nqy = 0.f, nqz = 0.f;

  for (int t = 0; t < 5; ++t) {
    const int tt = hb * 20 + wid * 5 + t;
    const int jb = tt * 16;

    // ---- build F (wave-private LDS, no block barrier) ----
    {
      int er = lane >> 2, c = lane & 3;
      int jr = jb + er;
      const float* ebase = (jr < NN)
          ? e + (((size_t)node * NN) + jr) * ED + c * 8
          : pe + (((size_t)node * NP) + (jr - NN)) * ED + c * 8;
      float4 e0 = *(const float4*)ebase;
      float4 e1 = *(const float4*)(ebase + 4);
      uint4 pw;
      pw.x = pk2(e0.x, e0.y); pw.y = pk2(e0.z, e0.w);
      pw.z = pk2(e1.x, e1.y); pw.w = pk2(e1.z, e1.w);
      *(uint4*)&sFw[er * 72 + c * 8] = pw;

      if (lane < 16) {
        int j = jb + lane;
        const float* qr = (j < NN) ? q + ((size_t)(b * NN + j)) * 4
                                   : pq + ((size_t)(b * NP + (j - NN))) * 4;
        float4 qj = *(const float4*)qr;
        const float* xr = (j < NN) ? x + ((size_t)(b * NN + j)) * 3
                                   : px + ((size_t)(b * NP + (j - NN))) * 3;
        float xj0 = xr[0], xj1 = xr[1], xj2 = xr[2];
        float d0 = xi0 - xj0, d1 = xi1 - xj1, d2v = xi2 - xj2;
        float d2 = d0 * d0 + d1 * d1 + d2v * d2v;
        float qdot = fabsf(qi0 * qj.x + qi1 * qj.y + qi2 * qj.z + qi3 * qj.w);
        float ajw = qj.x, ajx = -qj.y, ajy = -qj.z, ajz = -qj.w;  // conj
        float t0 = 2.f * (ajy * d2v - ajz * d1);
        float t1 = 2.f * (ajz * d0 - ajx * d2v);
        float t2 = 2.f * (ajx * d1 - ajy * d0);
        float lx0 = d0 + ajw * t0 + (ajy * t2 - ajz * t1);
        float lx1 = d1 + ajw * t1 + (ajz * t0 - ajx * t2);
        float lx2 = d2v + ajw * t2 + (ajx * t1 - ajy * t0);
        float lqw = ajw * qi0 - ajx * qi1 - ajy * qi2 - ajz * qi3;
        float lqx = ajw * qi1 + ajx * qi0 + ajy * qi3 - ajz * qi2;
        float lqy = ajw * qi2 - ajx * qi3 + ajy * qi0 + ajz * qi1;
        float lqz = ajw * qi3 + ajx * qi2 - ajy * qi1 + ajz * qi0;
        float nn2 = qj.x * qj.x + qj.y * qj.y + qj.z * qj.z + qj.w * qj.w;
        float rn = 1.f / fmaxf(sqrtf(nn2), 1e-12f);
        nqw = qj.x * rn; nqx = qj.y * rn; nqy = qj.z * rn; nqz = qj.w * rn;
        uint4 g0, g1;
        g0.x = pk2(lx0, lx1); g0.y = pk2(lx2, lqw);
        g0.z = pk2(lqx, lqy); g0.w = pk2(lqz, d2);
        g1.x = pk2(qdot, 0.f); g1.y = 0; g1.z = 0; g1.w = 0;
        *(uint4*)&sFw[lane * 72 + 32] = g0;
        *(uint4*)&sFw[lane * 72 + 40] = g1;
      }
    }

    // ---- layer 1: acc = Hi + Hall[j] + F@W1 ----
    const float* hp = Hall + (size_t)(b * NJ + jb) * 64;
    f32x4 acc[4];
#pragma unroll
    for (int nt = 0; nt < 4; ++nt)
#pragma unroll
      for (int r = 0; r < 4; ++r)
        acc[nt][r] = HiF[nt] + hp[(quad * 4 + r) * 64 + nt * 16 + nl];
#pragma unroll
    for (int ks = 0; ks < 2; ++ks) {
      short8 af = *(const short8*)&sFw[nl * 72 + ks * 32 + quad * 8];
#pragma unroll
      for (int nt = 0; nt < 4; ++nt) {
        short8 bfr = *(const short8*)&sW1B[(nt * 16 + nl) * 72 + ks * 32 + quad * 8];
        acc[nt] = __builtin_amdgcn_mfma_f32_16x16x32_bf16(af, bfr, acc[nt], 0, 0, 0);
      }
    }
#pragma unroll
    for (int nt = 0; nt < 4; ++nt)
#pragma unroll
      for (int r = 0; r < 4; ++r)
        sTw[(quad * 4 + r) * 72 + nt * 16 + nl] = f2bf(fmaxf(acc[nt][r], 0.f));

    // ---- layer 2: m = a1@W2 + bm2 (W2 regs); mask j==i; msum ----
#pragma unroll
    for (int nt = 0; nt < 4; ++nt)
      acc[nt] = (f32x4){bm2F[nt], bm2F[nt], bm2F[nt], bm2F[nt]};
#pragma unroll
    for (int ks = 0; ks < 2; ++ks) {
      short8 af = *(const short8*)&sTw[nl * 72 + ks * 32 + quad * 8];
#pragma unroll
      for (int nt = 0; nt < 4; ++nt)
        acc[nt] = __builtin_amdgcn_mfma_f32_16x16x32_bf16(af, W2f[nt][ks], acc[nt], 0, 0, 0);
    }
#pragma unroll
    for (int nt = 0; nt < 4; ++nt)
#pragma unroll
      for (int r = 0; r < 4; ++r) {
        int row = quad * 4 + r;
        float v = acc[nt][r];
        if (jb + row == i) v = 0.f;
        msum[nt][r] += v;
        sTw[row * 72 + nt * 16 + nl] = f2bf(v);
      }

    // ---- dx layer 1: x1 = relu(m@Wx1 + bx1) (Wx1 from LDS) ----
#pragma unroll
    for (int nt = 0; nt < 4; ++nt)
      acc[nt] = (f32x4){bx1F[nt], bx1F[nt], bx1F[nt], bx1F[nt]};
#pragma unroll
    for (int ks = 0; ks < 2; ++ks) {
      short8 af = *(const short8*)&sTw[nl * 72 + ks * 32 + quad * 8];
#pragma unroll
      for (int nt = 0; nt < 4; ++nt) {
        short8 bfr = *(const short8*)&sWx1B[(nt * 16 + nl) * 72 + ks * 32 + quad * 8];
        acc[nt] = __builtin_amdgcn_mfma_f32_16x16x32_bf16(af, bfr, acc[nt], 0, 0, 0);
      }
    }
#pragma unroll
    for (int nt = 0; nt < 4; ++nt)
#pragma unroll
      for (int r = 0; r < 4; ++r)
        sTw[(quad * 4 + r) * 72 + nt * 16 + nl] = f2bf(fmaxf(acc[nt][r], 0.f));

    // ---- dx layer 2: dx = x1@Wx2 + bx2 (cols 0..2) ----
    f32x4 dacc = (f32x4){bx2F, bx2F, bx2F, bx2F};
#pragma unroll
    for (int ks = 0; ks < 2; ++ks) {
      short8 af = *(const short8*)&sTw[nl * 72 + ks * 32 + quad * 8];
      dacc = __builtin_amdgcn_mfma_f32_16x16x32_bf16(af, Wx2f[ks], dacc, 0, 0, 0);
    }
    if (nl < 3) {
#pragma unroll
      for (int r = 0; r < 4; ++r) sDxT[wid][quad * 4 + r][nl] = dacc[r];
    }
    if (lane < 16) {
      int j = jb + lane;
      if (j != i) {
        float dxc0 = sDxT[wid][lane][0];
        float dxc1 = sDxT[wid][lane][1];
        float dxc2 = sDxT[wid][lane][2];
        float rt0 = 2.f * (nqy * dxc2 - nqz * dxc1);
        float rt1 = 2.f * (nqz * dxc0 - nqx * dxc2);
        float rt2 = 2.f * (nqx * dxc1 - nqy * dxc0);
        dxs0 += dxc0 + nqw * rt0 + (nqy * rt2 - nqz * rt1);
        dxs1 += dxc1 + nqw * rt1 + (nqz * rt0 - nqx * rt2);
        dxs2 += dxc2 + nqw * rt2 + (nqx * rt1 - nqy * rt0);
      }
    }
  }

  // ---- reductions + partial writes ----
#pragma unroll
  for (int nt = 0; nt < 4; ++nt) {
    float s = msum[nt][0] + msum[nt][1] + msum[nt][2] + msum[nt][3];
    s += __shfl_xor(s, 16);
    s += __shfl_xor(s, 32);
    if (lane < 16) sMsum[wid][nt * 16 + lane] = s;
  }
  {
    float a = dxs0, bb = dxs1, cc = dxs2;
#pragma unroll
    for (int off = 1; off < 16; off <<= 1) {
      a += __shfl_xor(a, off);
      bb += __shfl_xor(bb, off);
      cc += __shfl_xor(cc, off);
    }
    if (lane == 0) { sDxS[wid][0] = a; sDxS[wid][1] = bb; sDxS[wid][2] = cc; }
  }
  __syncthreads();
  if (wid == 0) {
    float ms = sMsum[0][lane] + sMsum[1][lane] + sMsum[2][lane] + sMsum[3][lane];
    pm[(size_t)node * 128 + hb * 64 + lane] = ms;
  } else if (wid == 1 && lane < 3) {
    float xs = sDxS[0][lane] + sDxS[1][lane] + sDxS[2][lane] + sDxS[3][lane];
    pdx[(size_t)node * 8 + hb * 4 + lane] = xs;
  }
}

// ---------------------------------------------------------------------------
// K3: per-node epilogues. grid = 512, 256 threads (4 waves, one per output).
// ---------------------------------------------------------------------------
__global__ void __launch_bounds__(256)
k3_epilogue(const float* __restrict__ q, const float* __restrict__ x,
            const float* __restrict__ h,
            const float* __restrict__ Wf1, const float* __restrict__ bf1,
            const float* __restrict__ Wf2, const float* __restrict__ bf2_,
            const float* __restrict__ Wq1, const float* __restrict__ bq1,
            const float* __restrict__ Wq2, const float* __restrict__ bq2,
            const float* __restrict__ Wt1, const float* __restrict__ bt1,
            const float* __restrict__ Wt2, const float* __restrict__ bt2,
            const float* __restrict__ pm, const float* __restrict__ pdx,
            float* __restrict__ out)
{
  __shared__ float sHi64[64], sMs[64], sPh[3][64];
  const size_t node = blockIdx.x;
  const int tid = threadIdx.x;
  const int wid = tid >> 6;
  const int lane = tid & 63;
  if (tid < 64) sHi64[tid] = h[node * 64 + tid];
  else if (tid < 128) {
    int c = tid - 64;
    sMs[c] = pm[node * 128 + c] + pm[node * 128 + 64 + c];
  }
  __syncthreads();

  if (wid == 0) {
    float f1a = bf1[lane], f1b = 0.f;
#pragma unroll 8
    for (int k = 0; k < 64; ++k) {
      f1a += sHi64[k] * Wf1[k * 64 + lane];
      f1b += sMs[k] * Wf1[(64 + k) * 64 + lane];
    }
    float f1 = fmaxf(f1a + f1b, 0.f);
    sPh[0][lane] = f1;
    float oacc = bf2_[lane];
#pragma unroll 8
    for (int k = 0; k < 64; ++k) oacc += sPh[0][k] * Wf2[k * 64 + lane];
    out[OFF_O + node * 64 + lane] = oacc;
  } else if (wid == 1) {
    float a = bq1[lane];
#pragma unroll 8
    for (int k = 0; k < 64; ++k) a += sMs[k] * Wq1[k * 64 + lane];
    a = fmaxf(a, 0.f);
    float p0 = a * Wq2[lane * 4 + 0];
    float p1 = a * Wq2[lane * 4 + 1];
    float p2 = a * Wq2[lane * 4 + 2];
    float p3 = a * Wq2[lane * 4 + 3];
#pragma unroll
    for (int off = 32; off >= 1; off >>= 1) {
      p0 += __shfl_xor(p0, off);
      p1 += __shfl_xor(p1, off);
      p2 += __shfl_xor(p2, off);
      p3 += __shfl_xor(p3, off);
    }
    float dq0 = p0 + bq2[0], dq1 = p1 + bq2[1];
    float dq2 = p2 + bq2[2], dq3 = p3 + bq2[3];
    float n = fmaxf(sqrtf(dq0 * dq0 + dq1 * dq1 + dq2 * dq2 + dq3 * dq3), 1e-12f);
    dq0 /= n; dq1 /= n; dq2 /= n; dq3 /= n;
    const float* qr = q + node * 4;
    float qi0 = qr[0], qi1 = qr[1], qi2 = qr[2], qi3 = qr[3];
    float uw = qi0 * dq0 - qi1 * dq1 - qi2 * dq2 - qi3 * dq3;
    float ux = qi0 * dq1 + qi1 * dq0 + qi2 * dq3 - qi3 * dq2;
    float uy = qi0 * dq2 - qi1 * dq3 + qi2 * dq0 + qi3 * dq1;
    float uz = qi0 * dq3 + qi1 * dq2 - qi2 * dq1 + qi3 * dq0;
    float n2 = fmaxf(sqrtf(uw * uw + ux * ux + uy * uy + uz * uz), 1e-12f);
    if (lane == 0) {
      float* po = out + OFF_Q + node * 4;
      po[0] = uw / n2; po[1] = ux / n2; po[2] = uy / n2; po[3] = uz / n2;
    }
  } else if (wid == 2) {
    float a = bt1[lane];
#pragma unroll 8
    for (int k = 0; k < 64; ++k) a += sMs[k] * Wt1[k * 64 + lane];
    a = fmaxf(a, 0.f);
    sPh[2][lane] = a;
    if (lane < 14) {
      float v = bt2[lane];
#pragma unroll 8
      for (int k = 0; k < 64; ++k) v += sPh[2][k] * Wt2[k * 14 + lane];
      float pv = __shfl_xor(v, 1);
      float nrm = fmaxf(sqrtf(v * v + pv * pv), 1e-12f);
      out[OFF_T + node * 14 + lane] = v / nrm;
    }
  } else {
    if (lane < 3) {
      float xs = pdx[node * 8 + lane] + pdx[node * 8 + 4 + lane];
      out[OFF_X + node * 3 + lane] = x[node * 3 + lane] + xs / 639.0f;
    }
  }
}

extern "C" void kernel_launch(void* const* d_in, const int* in_sizes, int n_in,
                              void* d_out, int out_size, void* d_ws, size_t ws_size,
                              hipStream_t stream) {
  const float* q   = (const float*)d_in[0];
  const float* x   = (const float*)d_in[1];
  const float* h   = (const float*)d_in[3];
  const float* e   = (const float*)d_in[4];
  const float* pq  = (const float*)d_in[6];
  const float* px  = (const float*)d_in[7];
  const float* pe  = (const float*)d_in[8];
  const float* ph  = (const float*)d_in[9];
  const float* Wm1 = (const float*)d_in[11];
  const float* bm1 = (const float*)d_in[12];
  const float* Wm2 = (const float*)d_in[13];
  const float* bm2 = (const float*)d_in[14];
  const float* Wf1 = (const float*)d_in[15];
  const float* bf1 = (const float*)d_in[16];
  const float* Wf2 = (const float*)d_in[17];
  const float* bf2_ = (const float*)d_in[18];
  const float* Wx1 = (const float*)d_in[19];
  const float* bx1 = (const float*)d_in[20];
  const float* Wx2 = (const float*)d_in[21];
  const float* bx2 = (const float*)d_in[22];
  const float* Wq1 = (const float*)d_in[23];
  const float* bq1 = (const float*)d_in[24];
  const float* Wq2 = (const float*)d_in[25];
  const float* bq2 = (const float*)d_in[26];
  const float* Wt1 = (const float*)d_in[27];
  const float* bt1 = (const float*)d_in[28];
  const float* Wt2 = (const float*)d_in[29];
  const float* bt2 = (const float*)d_in[30];

  float* ws = (float*)d_ws;
  float* Hall = ws + WS_HALL;
  float* Hi   = ws + WS_HI;
  float* pm   = ws + WS_PM;
  float* pdx  = ws + WS_PDX;

  k1_precompute<<<48, 256, 0, stream>>>(h, ph, Wm1, bm1, Hall, Hi);

  k2_edges<<<NB * NN * 2, 256, 0, stream>>>(
      q, x, e, pe, pq, px, Wm1, Wm2, bm2, Wx1, bx1, Wx2, bx2,
      Hall, Hi, pm, pdx);

  k3_epilogue<<<NB * NN, 256, 0, stream>>>(
      q, x, h, Wf1, bf1, Wf2, bf2_, Wq1, bq1, Wq2, bq2,
      Wt1, bt1, Wt2, bt2, pm, pdx, (float*)d_out);
}

// Round 8
// 222.644 us; speedup vs baseline: 1.1344x; 1.1310x over previous
//
#include <hip/hip_runtime.h>
#include <stdint.h>

#define NB 4
#define NN 128
#define NP 512
#define NJ 640
#define HD 64
#define ED 32

typedef unsigned short u16;
typedef __attribute__((ext_vector_type(8))) short short8;
typedef __attribute__((ext_vector_type(4))) float f32x4;

// out element offsets (f32): upd_q[2048], upd_x[1536], tor[7168], o[32768]
#define OFF_Q 0
#define OFF_X 2048
#define OFF_T 3584
#define OFF_O 10752

// d_ws float offsets
#define WS_HALL 0         // 4*640*64 = 163840
#define WS_HI   163840    // 512*64   = 32768
#define WS_PM   196608    // 512*3*64 = 98304
#define WS_PDX  294912    // 512*3*4  = 6144

__device__ __forceinline__ u16 f2bf(float f) {
  union { float f; uint32_t i; } v; v.f = f;
  uint32_t x = v.i;
  return (u16)((x + 0x7FFFu + ((x >> 16) & 1u)) >> 16);
}
__device__ __forceinline__ uint32_t pk2(float a, float b) {
  return (uint32_t)f2bf(a) | ((uint32_t)f2bf(b) << 16);
}

// ---------------------------------------------------------------------------
// K1: Hall[b,j,:] = h_all[b,j]@Wm1[64:128]; Hi[node,:] = h[node]@Wm1[0:64]+bm1
// grid = 192 blocks x 256. Blocks 0..159: Hall, 16 rows each; 160..191: Hi.
// ---------------------------------------------------------------------------
__global__ void __launch_bounds__(256)
k1_precompute(const float* __restrict__ h, const float* __restrict__ ph,
              const float* __restrict__ Wm1, const float* __restrict__ bm1,
              float* __restrict__ Hall, float* __restrict__ Hi)
{
  __shared__ float sW[64 * 64];
  const int blk = blockIdx.x;
  const int tid = threadIdx.x;
  const bool isHi = blk >= 160;
  const int wofs = isHi ? 0 : 64;
  for (int idx = tid; idx < 4096; idx += 256)
    sW[idx] = Wm1[(size_t)(wofs + (idx >> 6)) * 64 + (idx & 63)];
  __syncthreads();
  const int lane = tid & 63;
  const int wid = tid >> 6;
  const int base = (isHi ? (blk - 160) : blk) * 16 + wid * 4;
  const float* hr[4];
#pragma unroll
  for (int u = 0; u < 4; ++u) {
    int rr = base + u;
    if (isHi) hr[u] = h + (size_t)rr * 64;
    else {
      int bb = rr / NJ, j = rr % NJ;
      hr[u] = (j < NN) ? h + (size_t)(bb * NN + j) * 64
                       : ph + (size_t)(bb * NP + (j - NN)) * 64;
    }
  }
  float a0 = isHi ? bm1[lane] : 0.f, a1 = a0, a2 = a0, a3 = a0;
#pragma unroll 8
  for (int k = 0; k < 64; ++k) {
    float w = sW[k * 64 + lane];
    a0 += hr[0][k] * w; a1 += hr[1][k] * w;
    a2 += hr[2][k] * w; a3 += hr[3][k] * w;
  }
  float* dst = isHi ? Hi : Hall;
  dst[(size_t)(base + 0) * 64 + lane] = a0;
  dst[(size_t)(base + 1) * 64 + lane] = a1;
  dst[(size_t)(base + 2) * 64 + lane] = a2;
  dst[(size_t)(base + 3) * 64 + lane] = a3;
}

// ---------------------------------------------------------------------------
// K2: edge loop. grid = 1536 (node x 3 parts: 14/14/12 tiles), 256 threads.
// F layout (bf16, 72-short rows): k0..31=e, k32..40=geo, k41..63=0.
// __launch_bounds__(256,3): 170-reg budget -> no spill, 3 blocks/CU,
// grid 1536 = exactly 2 rounds of 768 co-resident blocks.
// ---------------------------------------------------------------------------
__global__ void __launch_bounds__(256, 3)
k2_edges(const float* __restrict__ q, const float* __restrict__ x,
         const float* __restrict__ e, const float* __restrict__ pe,
         const float* __restrict__ pq, const float* __restrict__ px,
         const float* __restrict__ Wm1, const float* __restrict__ Wm2,
         const float* __restrict__ bm2, const float* __restrict__ Wx1,
         const float* __restrict__ bx1, const float* __restrict__ Wx2,
         const float* __restrict__ bx2,
         const float* __restrict__ Hall, const float* __restrict__ Hi,
         float* __restrict__ pm, float* __restrict__ pdx)
{
  __shared__ u16 sW1B[64 * 72];    // W1 (K=64 compact), [n][k]
  __shared__ u16 sWx1B[64 * 72];   // Wx1, [n][k]
  __shared__ u16 sF[4][16 * 72];   // per-wave feature tile
  __shared__ u16 sT[4][16 * 72];   // per-wave transform buffer
  __shared__ float sDxT[4][16][4];
  __shared__ float sMsum[4][64];
  __shared__ float sDxS[4][4];

  const int node = blockIdx.x / 3;
  const int part = blockIdx.x % 3;
  const int tstart = part * 14;             // 0, 14, 28
  const int tcnt = (part == 2) ? 12 : 14;
  const int b = node >> 7;
  const int i = node & 127;
  const int tid = threadIdx.x;
  const int wid = tid >> 6;
  const int lane = tid & 63;
  const int nl = lane & 15;
  const int quad = lane >> 4;

  u16* sFw = sF[wid];
  u16* sTw = sT[wid];

  // stage W1 / Wx1 to LDS (bf16, [n][k])
  for (int idx = tid; idx < 64 * 64; idx += 256) {
    int n = idx >> 6, k = idx & 63;
    int row = (k < 32) ? (128 + k) : ((k < 41) ? (160 + (k - 32)) : -1);
    sW1B[n * 72 + k] = (row < 0) ? (u16)0 : f2bf(Wm1[(size_t)row * 64 + n]);
    sWx1B[n * 72 + k] = f2bf(Wx1[(size_t)k * 64 + n]);
  }
  // zero own F tile (pad cols 41..63 stay zero; live cols rewritten per tile)
  for (int idx = lane; idx < 16 * 72 / 2; idx += 64) ((uint32_t*)sFw)[idx] = 0;

  const float* qr0 = q + (size_t)node * 4;
  const float qi0 = qr0[0], qi1 = qr0[1], qi2 = qr0[2], qi3 = qr0[3];
  const float* xr0 = x + (size_t)node * 3;
  const float xi0 = xr0[0], xi1 = xr0[1], xi2 = xr0[2];

  // register B-frags: W2 (32 VGPR) + Wx2 (8 VGPR)
  short8 W2f[4][2], Wx2f[2];
#pragma unroll
  for (int nt = 0; nt < 4; ++nt)
#pragma unroll
    for (int ks = 0; ks < 2; ++ks) {
      short8 v;
#pragma unroll
      for (int jj = 0; jj < 8; ++jj) {
        int k = ks * 32 + quad * 8 + jj;
        v[jj] = (short)f2bf(Wm2[(size_t)k * 64 + nt * 16 + nl]);
      }
      W2f[nt][ks] = v;
    }
#pragma unroll
  for (int ks = 0; ks < 2; ++ks) {
    short8 v;
#pragma unroll
    for (int jj = 0; jj < 8; ++jj) {
      int k = ks * 32 + quad * 8 + jj;
      v[jj] = (nl < 3) ? (short)f2bf(Wx2[(size_t)k * 3 + nl]) : (short)0;
    }
    Wx2f[ks] = v;
  }

  float HiF[4], bm2F[4], bx1F[4];
#pragma unroll
  for (int nt = 0; nt < 4; ++nt) {
    HiF[nt] = Hi[(size_t)node * 64 + nt * 16 + nl];
    bm2F[nt] = bm2[nt * 16 + nl];
    bx1F[nt] = bx1[nt * 16 + nl];
  }
  const float bx2F = (nl < 3) ? bx2[nl] : 0.f;

  __syncthreads();  // W1/Wx1 staged

  f32x4 msum[4];
#pragma unroll
  for (int nt = 0; nt < 4; ++nt) msum[nt] = (f32x4){0.f, 0.f, 0.f, 0.f};
  float dxs0 = 0.f, dxs1 = 0.f, dxs2 = 0.f;
  float nqw = 0.f, nqx = 0.f, nqy = 0.f, nqz = 0.f;

  for (int t = wid; t < tcnt; t += 4) {
    const int jb = (tstart + t) * 16;

    // ---- build F (wave-private LDS, no block barrier) ----
    {
      int er = lane >> 2, c = lane & 3;
      int jr = jb + er;
      const float* ebase = (jr < NN)
          ? e + (((size_t)node * NN) + jr) * ED + c * 8
          : pe + (((size_t)node * NP) + (jr - NN)) * ED + c * 8;
      float4 e0 = *(const float4*)ebase;
      float4 e1 = *(const float4*)(ebase + 4);
      uint4 pw;
      pw.x = pk2(e0.x, e0.y); pw.y = pk2(e0.z, e0.w);
      pw.z = pk2(e1.x, e1.y); pw.w = pk2(e1.z, e1.w);
      *(uint4*)&sFw[er * 72 + c * 8] = pw;

      if (lane < 16) {
        int j = jb + lane;
        const float* qr = (j < NN) ? q + ((size_t)(b * NN + j)) * 4
                                   : pq + ((size_t)(b * NP + (j - NN))) * 4;
        float4 qj = *(const float4*)qr;
        const float* xr = (j < NN) ? x + ((size_t)(b * NN + j)) * 3
                                   : px + ((size_t)(b * NP + (j - NN))) * 3;
        float xj0 = xr[0], xj1 = xr[1], xj2 = xr[2];
        float d0 = xi0 - xj0, d1 = xi1 - xj1, d2v = xi2 - xj2;
        float d2 = d0 * d0 + d1 * d1 + d2v * d2v;
        float qdot = fabsf(qi0 * qj.x + qi1 * qj.y + qi2 * qj.z + qi3 * qj.w);
        float ajw = qj.x, ajx = -qj.y, ajy = -qj.z, ajz = -qj.w;  // conj
        float t0 = 2.f * (ajy * d2v - ajz * d1);
        float t1 = 2.f * (ajz * d0 - ajx * d2v);
        float t2 = 2.f * (ajx * d1 - ajy * d0);
        float lx0 = d0 + ajw * t0 + (ajy * t2 - ajz * t1);
        float lx1 = d1 + ajw * t1 + (ajz * t0 - ajx * t2);
        float lx2 = d2v + ajw * t2 + (ajx * t1 - ajy * t0);
        float lqw = ajw * qi0 - ajx * qi1 - ajy * qi2 - ajz * qi3;
        float lqx = ajw * qi1 + ajx * qi0 + ajy * qi3 - ajz * qi2;
        float lqy = ajw * qi2 - ajx * qi3 + ajy * qi0 + ajz * qi1;
        float lqz = ajw * qi3 + ajx * qi2 - ajy * qi1 + ajz * qi0;
        float nn2 = qj.x * qj.x + qj.y * qj.y + qj.z * qj.z + qj.w * qj.w;
        float rn = 1.f / fmaxf(sqrtf(nn2), 1e-12f);
        nqw = qj.x * rn; nqx = qj.y * rn; nqy = qj.z * rn; nqz = qj.w * rn;
        uint4 g0, g1;
        g0.x = pk2(lx0, lx1); g0.y = pk2(lx2, lqw);
        g0.z = pk2(lqx, lqy); g0.w = pk2(lqz, d2);
        g1.x = pk2(qdot, 0.f); g1.y = 0; g1.z = 0; g1.w = 0;
        *(uint4*)&sFw[lane * 72 + 32] = g0;
        *(uint4*)&sFw[lane * 72 + 40] = g1;
      }
    }

    // ---- layer 1: acc = Hi + Hall[j] + F@W1 ----
    const float* hp = Hall + (size_t)(b * NJ + jb) * 64;
    f32x4 acc[4];
#pragma unroll
    for (int nt = 0; nt < 4; ++nt)
#pragma unroll
      for (int r = 0; r < 4; ++r)
        acc[nt][r] = HiF[nt] + hp[(quad * 4 + r) * 64 + nt * 16 + nl];
#pragma unroll
    for (int ks = 0; ks < 2; ++ks) {
      short8 af = *(const short8*)&sFw[nl * 72 + ks * 32 + quad * 8];
#pragma unroll
      for (int nt = 0; nt < 4; ++nt) {
        short8 bfr = *(const short8*)&sW1B[(nt * 16 + nl) * 72 + ks * 32 + quad * 8];
        acc[nt] = __builtin_amdgcn_mfma_f32_16x16x32_bf16(af, bfr, acc[nt], 0, 0, 0);
      }
    }
#pragma unroll
    for (int nt = 0; nt < 4; ++nt)
#pragma unroll
      for (int r = 0; r < 4; ++r)
        sTw[(quad * 4 + r) * 72 + nt * 16 + nl] = f2bf(fmaxf(acc[nt][r], 0.f));

    // ---- layer 2: m = a1@W2 + bm2 (W2 regs); mask j==i; msum ----
#pragma unroll
    for (int nt = 0; nt < 4; ++nt)
      acc[nt] = (f32x4){bm2F[nt], bm2F[nt], bm2F[nt], bm2F[nt]};
#pragma unroll
    for (int ks = 0; ks < 2; ++ks) {
      short8 af = *(const short8*)&sTw[nl * 72 + ks * 32 + quad * 8];
#pragma unroll
      for (int nt = 0; nt < 4; ++nt)
        acc[nt] = __builtin_amdgcn_mfma_f32_16x16x32_bf16(af, W2f[nt][ks], acc[nt], 0, 0, 0);
    }
#pragma unroll
    for (int nt = 0; nt < 4; ++nt)
#pragma unroll
      for (int r = 0; r < 4; ++r) {
        int row = quad * 4 + r;
        float v = acc[nt][r];
        if (jb + row == i) v = 0.f;
        msum[nt][r] += v;
        sTw[row * 72 + nt * 16 + nl] = f2bf(v);
      }

    // ---- dx layer 1: x1 = relu(m@Wx1 + bx1) (Wx1 from LDS) ----
#pragma unroll
    for (int nt = 0; nt < 4; ++nt)
      acc[nt] = (f32x4){bx1F[nt], bx1F[nt], bx1F[nt], bx1F[nt]};
#pragma unroll
    for (int ks = 0; ks < 2; ++ks) {
      short8 af = *(const short8*)&sTw[nl * 72 + ks * 32 + quad * 8];
#pragma unroll
      for (int nt = 0; nt < 4; ++nt) {
        short8 bfr = *(const short8*)&sWx1B[(nt * 16 + nl) * 72 + ks * 32 + quad * 8];
        acc[nt] = __builtin_amdgcn_mfma_f32_16x16x32_bf16(af, bfr, acc[nt], 0, 0, 0);
      }
    }
#pragma unroll
    for (int nt = 0; nt < 4; ++nt)
#pragma unroll
      for (int r = 0; r < 4; ++r)
        sTw[(quad * 4 + r) * 72 + nt * 16 + nl] = f2bf(fmaxf(acc[nt][r], 0.f));

    // ---- dx layer 2: dx = x1@Wx2 + bx2 (cols 0..2) ----
    f32x4 dacc = (f32x4){bx2F, bx2F, bx2F, bx2F};
#pragma unroll
    for (int ks = 0; ks < 2; ++ks) {
      short8 af = *(const short8*)&sTw[nl * 72 + ks * 32 + quad * 8];
      dacc = __builtin_amdgcn_mfma_f32_16x16x32_bf16(af, Wx2f[ks], dacc, 0, 0, 0);
    }
    if (nl < 3) {
#pragma unroll
      for (int r = 0; r < 4; ++r) sDxT[wid][quad * 4 + r][nl] = dacc[r];
    }
    if (lane < 16) {
      int j = jb + lane;
      if (j != i) {
        float dxc0 = sDxT[wid][lane][0];
        float dxc1 = sDxT[wid][lane][1];
        float dxc2 = sDxT[wid][lane][2];
        float rt0 = 2.f * (nqy * dxc2 - nqz * dxc1);
        float rt1 = 2.f * (nqz * dxc0 - nqx * dxc2);
        float rt2 = 2.f * (nqx * dxc1 - nqy * dxc0);
        dxs0 += dxc0 + nqw * rt0 + (nqy * rt2 - nqz * rt1);
        dxs1 += dxc1 + nqw * rt1 + (nqz * rt0 - nqx * rt2);
        dxs2 += dxc2 + nqw * rt2 + (nqx * rt1 - nqy * rt0);
      }
    }
  }

  // ---- reductions + partial writes ----
#pragma unroll
  for (int nt = 0; nt < 4; ++nt) {
    float s = msum[nt][0] + msum[nt][1] + msum[nt][2] + msum[nt][3];
    s += __shfl_xor(s, 16);
    s += __shfl_xor(s, 32);
    if (lane < 16) sMsum[wid][nt * 16 + lane] = s;
  }
  {
    float a = dxs0, bb = dxs1, cc = dxs2;
#pragma unroll
    for (int off = 1; off < 16; off <<= 1) {
      a += __shfl_xor(a, off);
      bb += __shfl_xor(bb, off);
      cc += __shfl_xor(cc, off);
    }
    if (lane == 0) { sDxS[wid][0] = a; sDxS[wid][1] = bb; sDxS[wid][2] = cc; }
  }
  __syncthreads();
  if (wid == 0) {
    float ms = sMsum[0][lane] + sMsum[1][lane] + sMsum[2][lane] + sMsum[3][lane];
    pm[(size_t)node * 192 + part * 64 + lane] = ms;
  } else if (wid == 1 && lane < 3) {
    float xs = sDxS[0][lane] + sDxS[1][lane] + sDxS[2][lane] + sDxS[3][lane];
    pdx[(size_t)node * 12 + part * 4 + lane] = xs;
  }
}

// ---------------------------------------------------------------------------
// K3: per-node epilogues. grid = 512, 256 threads (4 waves, one per output).
// ---------------------------------------------------------------------------
__global__ void __launch_bounds__(256)
k3_epilogue(const float* __restrict__ q, const float* __restrict__ x,
            const float* __restrict__ h,
            const float* __restrict__ Wf1, const float* __restrict__ bf1,
            const float* __restrict__ Wf2, const float* __restrict__ bf2_,
            const float* __restrict__ Wq1, const float* __restrict__ bq1,
            const float* __restrict__ Wq2, const float* __restrict__ bq2,
            const float* __restrict__ Wt1, const float* __restrict__ bt1,
            const float* __restrict__ Wt2, const float* __restrict__ bt2,
            const float* __restrict__ pm, const float* __restrict__ pdx,
            float* __restrict__ out)
{
  __shared__ float sHi64[64], sMs[64], sPh[3][64];
  const size_t node = blockIdx.x;
  const int tid = threadIdx.x;
  const int wid = tid >> 6;
  const int lane = tid & 63;
  if (tid < 64) sHi64[tid] = h[node * 64 + tid];
  else if (tid < 128) {
    int c = tid - 64;
    sMs[c] = pm[node * 192 + c] + pm[node * 192 + 64 + c] + pm[node * 192 + 128 + c];
  }
  __syncthreads();

  if (wid == 0) {
    float f1a = bf1[lane], f1b = 0.f;
#pragma unroll 8
    for (int k = 0; k < 64; ++k) {
      f1a += sHi64[k] * Wf1[k * 64 + lane];
      f1b += sMs[k] * Wf1[(64 + k) * 64 + lane];
    }
    float f1 = fmaxf(f1a + f1b, 0.f);
    sPh[0][lane] = f1;
    float oacc = bf2_[lane];
#pragma unroll 8
    for (int k = 0; k < 64; ++k) oacc += sPh[0][k] * Wf2[k * 64 + lane];
    out[OFF_O + node * 64 + lane] = oacc;
  } else if (wid == 1) {
    float a = bq1[lane];
#pragma unroll 8
    for (int k = 0; k < 64; ++k) a += sMs[k] * Wq1[k * 64 + lane];
    a = fmaxf(a, 0.f);
    float p0 = a * Wq2[lane * 4 + 0];
    float p1 = a * Wq2[lane * 4 + 1];
    float p2 = a * Wq2[lane * 4 + 2];
    float p3 = a * Wq2[lane * 4 + 3];
#pragma unroll
    for (int off = 32; off >= 1; off >>= 1) {
      p0 += __shfl_xor(p0, off);
      p1 += __shfl_xor(p1, off);
      p2 += __shfl_xor(p2, off);
      p3 += __shfl_xor(p3, off);
    }
    float dq0 = p0 + bq2[0], dq1 = p1 + bq2[1];
    float dq2 = p2 + bq2[2], dq3 = p3 + bq2[3];
    float n = fmaxf(sqrtf(dq0 * dq0 + dq1 * dq1 + dq2 * dq2 + dq3 * dq3), 1e-12f);
    dq0 /= n; dq1 /= n; dq2 /= n; dq3 /= n;
    const float* qr = q + node * 4;
    float qi0 = qr[0], qi1 = qr[1], qi2 = qr[2], qi3 = qr[3];
    float uw = qi0 * dq0 - qi1 * dq1 - qi2 * dq2 - qi3 * dq3;
    float ux = qi0 * dq1 + qi1 * dq0 + qi2 * dq3 - qi3 * dq2;
    float uy = qi0 * dq2 - qi1 * dq3 + qi2 * dq0 + qi3 * dq1;
    float uz = qi0 * dq3 + qi1 * dq2 - qi2 * dq1 + qi3 * dq0;
    float n2 = fmaxf(sqrtf(uw * uw + ux * ux + uy * uy + uz * uz), 1e-12f);
    if (lane == 0) {
      float* po = out + OFF_Q + node * 4;
      po[0] = uw / n2; po[1] = ux / n2; po[2] = uy / n2; po[3] = uz / n2;
    }
  } else if (wid == 2) {
    float a = bt1[lane];
#pragma unroll 8
    for (int k = 0; k < 64; ++k) a += sMs[k] * Wt1[k * 64 + lane];
    a = fmaxf(a, 0.f);
    sPh[2][lane] = a;
    if (lane < 14) {
      float v = bt2[lane];
#pragma unroll 8
      for (int k = 0; k < 64; ++k) v += sPh[2][k] * Wt2[k * 14 + lane];
      float pv = __shfl_xor(v, 1);
      float nrm = fmaxf(sqrtf(v * v + pv * pv), 1e-12f);
      out[OFF_T + node * 14 + lane] = v / nrm;
    }
  } else {
    if (lane < 3) {
      float xs = pdx[node * 12 + lane] + pdx[node * 12 + 4 + lane] +
                 pdx[node * 12 + 8 + lane];
      out[OFF_X + node * 3 + lane] = x[node * 3 + lane] + xs / 639.0f;
    }
  }
}

extern "C" void kernel_launch(void* const* d_in, const int* in_sizes, int n_in,
                              void* d_out, int out_size, void* d_ws, size_t ws_size,
                              hipStream_t stream) {
  const float* q   = (const float*)d_in[0];
  const float* x   = (const float*)d_in[1];
  const float* h   = (const float*)d_in[3];
  const float* e   = (const float*)d_in[4];
  const float* pq  = (const float*)d_in[6];
  const float* px  = (const float*)d_in[7];
  const float* pe  = (const float*)d_in[8];
  const float* ph  = (const float*)d_in[9];
  const float* Wm1 = (const float*)d_in[11];
  const float* bm1 = (const float*)d_in[12];
  const float* Wm2 = (const float*)d_in[13];
  const float* bm2 = (const float*)d_in[14];
  const float* Wf1 = (const float*)d_in[15];
  const float* bf1 = (const float*)d_in[16];
  const float* Wf2 = (const float*)d_in[17];
  const float* bf2_ = (const float*)d_in[18];
  const float* Wx1 = (const float*)d_in[19];
  const float* bx1 = (const float*)d_in[20];
  const float* Wx2 = (const float*)d_in[21];
  const float* bx2 = (const float*)d_in[22];
  const float* Wq1 = (const float*)d_in[23];
  const float* bq1 = (const float*)d_in[24];
  const float* Wq2 = (const float*)d_in[25];
  const float* bq2 = (const float*)d_in[26];
  const float* Wt1 = (const float*)d_in[27];
  const float* bt1 = (const float*)d_in[28];
  const float* Wt2 = (const float*)d_in[29];
  const float* bt2 = (const float*)d_in[30];

  float* ws = (float*)d_ws;
  float* Hall = ws + WS_HALL;
  float* Hi   = ws + WS_HI;
  float* pm   = ws + WS_PM;
  float* pdx  = ws + WS_PDX;

  k1_precompute<<<192, 256, 0, stream>>>(h, ph, Wm1, bm1, Hall, Hi);

  k2_edges<<<NB * NN * 3, 256, 0, stream>>>(
      q, x, e, pe, pq, px, Wm1, Wm2, bm2, Wx1, bx1, Wx2, bx2,
      Hall, Hi, pm, pdx);

  k3_epilogue<<<NB * NN, 256, 0, stream>>>(
      q, x, h, Wf1, bf1, Wf2, bf2_, Wq1, bq1, Wq2, bq2,
      Wt1, bt1, Wt2, bt2, pm, pdx, (float*)d_out);
}

// Round 9
// 220.714 us; speedup vs baseline: 1.1443x; 1.0087x over previous
//
#include <hip/hip_runtime.h>
#include <stdint.h>

#define NB 4
#define NN 128
#define NP 512
#define NJ 640
#define HD 64
#define ED 32

typedef unsigned short u16;
typedef __attribute__((ext_vector_type(8))) short short8;
typedef __attribute__((ext_vector_type(4))) float f32x4;

// out element offsets (f32): upd_q[2048], upd_x[1536], tor[7168], o[32768]
#define OFF_Q 0
#define OFF_X 2048
#define OFF_T 3584
#define OFF_O 10752

// d_ws float offsets
#define WS_HALL 0         // 4*640*64 = 163840
#define WS_HI   163840    // 512*64   = 32768
#define WS_PM   196608    // 512*4*64 = 131072
#define WS_PDX  327680    // 512*4*4  = 8192

__device__ __forceinline__ u16 f2bf(float f) {
  union { float f; uint32_t i; } v; v.f = f;
  uint32_t x = v.i;
  return (u16)((x + 0x7FFFu + ((x >> 16) & 1u)) >> 16);
}
__device__ __forceinline__ uint32_t pk2(float a, float b) {
  return (uint32_t)f2bf(a) | ((uint32_t)f2bf(b) << 16);
}

// ---------------------------------------------------------------------------
// K1: Hall[b,j,:] = h_all[b,j]@Wm1[64:128]; Hi[node,:] = h[node]@Wm1[0:64]+bm1
// grid = 192 blocks x 256. Blocks 0..159: Hall, 16 rows each; 160..191: Hi.
// ---------------------------------------------------------------------------
__global__ void __launch_bounds__(256)
k1_precompute(const float* __restrict__ h, const float* __restrict__ ph,
              const float* __restrict__ Wm1, const float* __restrict__ bm1,
              float* __restrict__ Hall, float* __restrict__ Hi)
{
  __shared__ float sW[64 * 64];
  const int blk = blockIdx.x;
  const int tid = threadIdx.x;
  const bool isHi = blk >= 160;
  const int wofs = isHi ? 0 : 64;
  for (int idx = tid; idx < 4096; idx += 256)
    sW[idx] = Wm1[(size_t)(wofs + (idx >> 6)) * 64 + (idx & 63)];
  __syncthreads();
  const int lane = tid & 63;
  const int wid = tid >> 6;
  const int base = (isHi ? (blk - 160) : blk) * 16 + wid * 4;
  const float* hr[4];
#pragma unroll
  for (int u = 0; u < 4; ++u) {
    int rr = base + u;
    if (isHi) hr[u] = h + (size_t)rr * 64;
    else {
      int bb = rr / NJ, j = rr % NJ;
      hr[u] = (j < NN) ? h + (size_t)(bb * NN + j) * 64
                       : ph + (size_t)(bb * NP + (j - NN)) * 64;
    }
  }
  float a0 = isHi ? bm1[lane] : 0.f, a1 = a0, a2 = a0, a3 = a0;
#pragma unroll 8
  for (int k = 0; k < 64; ++k) {
    float w = sW[k * 64 + lane];
    a0 += hr[0][k] * w; a1 += hr[1][k] * w;
    a2 += hr[2][k] * w; a3 += hr[3][k] * w;
  }
  float* dst = isHi ? Hi : Hall;
  dst[(size_t)(base + 0) * 64 + lane] = a0;
  dst[(size_t)(base + 1) * 64 + lane] = a1;
  dst[(size_t)(base + 2) * 64 + lane] = a2;
  dst[(size_t)(base + 3) * 64 + lane] = a3;
}

// ---------------------------------------------------------------------------
// K2: edge loop. grid = 2048 (node x 4 parts, 10 tiles each), 256 threads.
// F layout (bf16, 72-short rows): k0..31=e, k32..40=geo, k41..63=0.
// NO min-waves launch bound: letting the allocator pick (round 5: 120 regs,
// zero spill) beats every forced split tried (rounds 4/6/7/8 all spilled).
// ---------------------------------------------------------------------------
__global__ void __launch_bounds__(256)
k2_edges(const float* __restrict__ q, const float* __restrict__ x,
         const float* __restrict__ e, const float* __restrict__ pe,
         const float* __restrict__ pq, const float* __restrict__ px,
         const float* __restrict__ Wm1, const float* __restrict__ Wm2,
         const float* __restrict__ bm2, const float* __restrict__ Wx1,
         const float* __restrict__ bx1, const float* __restrict__ Wx2,
         const float* __restrict__ bx2,
         const float* __restrict__ Hall, const float* __restrict__ Hi,
         float* __restrict__ pm, float* __restrict__ pdx)
{
  __shared__ u16 sW1B[64 * 72];    // W1 (K=64 compact), [n][k]
  __shared__ u16 sWx1B[64 * 72];   // Wx1, [n][k]
  __shared__ u16 sF[4][16 * 72];   // per-wave feature tile
  __shared__ u16 sT[4][16 * 72];   // per-wave transform buffer
  __shared__ float sDxT[4][16][4];
  __shared__ float sMsum[4][64];
  __shared__ float sDxS[4][4];

  const int node = blockIdx.x >> 2;
  const int part = blockIdx.x & 3;
  const int tstart = part * 10;
  const int b = node >> 7;
  const int i = node & 127;
  const int tid = threadIdx.x;
  const int wid = tid >> 6;
  const int lane = tid & 63;
  const int nl = lane & 15;
  const int quad = lane >> 4;

  u16* sFw = sF[wid];
  u16* sTw = sT[wid];

  // stage W1 / Wx1 to LDS (bf16, [n][k])
  for (int idx = tid; idx < 64 * 64; idx += 256) {
    int n = idx >> 6, k = idx & 63;
    int row = (k < 32) ? (128 + k) : ((k < 41) ? (160 + (k - 32)) : -1);
    sW1B[n * 72 + k] = (row < 0) ? (u16)0 : f2bf(Wm1[(size_t)row * 64 + n]);
    sWx1B[n * 72 + k] = f2bf(Wx1[(size_t)k * 64 + n]);
  }
  // zero own F tile (pad cols 41..63 stay zero; live cols rewritten per tile)
  for (int idx = lane; idx < 16 * 72 / 2; idx += 64) ((uint32_t*)sFw)[idx] = 0;

  const float* qr0 = q + (size_t)node * 4;
  const float qi0 = qr0[0], qi1 = qr0[1], qi2 = qr0[2], qi3 = qr0[3];
  const float* xr0 = x + (size_t)node * 3;
  const float xi0 = xr0[0], xi1 = xr0[1], xi2 = xr0[2];

  // register B-frags: W2 (32 VGPR) + Wx2 (8 VGPR)
  short8 W2f[4][2], Wx2f[2];
#pragma unroll
  for (int nt = 0; nt < 4; ++nt)
#pragma unroll
    for (int ks = 0; ks < 2; ++ks) {
      short8 v;
#pragma unroll
      for (int jj = 0; jj < 8; ++jj) {
        int k = ks * 32 + quad * 8 + jj;
        v[jj] = (short)f2bf(Wm2[(size_t)k * 64 + nt * 16 + nl]);
      }
      W2f[nt][ks] = v;
    }
#pragma unroll
  for (int ks = 0; ks < 2; ++ks) {
    short8 v;
#pragma unroll
    for (int jj = 0; jj < 8; ++jj) {
      int k = ks * 32 + quad * 8 + jj;
      v[jj] = (nl < 3) ? (short)f2bf(Wx2[(size_t)k * 3 + nl]) : (short)0;
    }
    Wx2f[ks] = v;
  }

  float HiF[4], bm2F[4], bx1F[4];
#pragma unroll
  for (int nt = 0; nt < 4; ++nt) {
    HiF[nt] = Hi[(size_t)node * 64 + nt * 16 + nl];
    bm2F[nt] = bm2[nt * 16 + nl];
    bx1F[nt] = bx1[nt * 16 + nl];
  }
  const float bx2F = (nl < 3) ? bx2[nl] : 0.f;

  __syncthreads();  // W1/Wx1 staged

  f32x4 msum[4];
#pragma unroll
  for (int nt = 0; nt < 4; ++nt) msum[nt] = (f32x4){0.f, 0.f, 0.f, 0.f};
  float dxs0 = 0.f, dxs1 = 0.f, dxs2 = 0.f;
  float nqw = 0.f, nqx = 0.f, nqy = 0.f, nqz = 0.f;

  for (int t = wid; t < 10; t += 4) {
    const int jb = (tstart + t) * 16;

    // ---- build F (wave-private LDS, no block barrier) ----
    {
      int er = lane >> 2, c = lane & 3;
      int jr = jb + er;
      const float* ebase = (jr < NN)
          ? e + (((size_t)node * NN) + jr) * ED + c * 8
          : pe + (((size_t)node * NP) + (jr - NN)) * ED + c * 8;
      float4 e0 = *(const float4*)ebase;
      float4 e1 = *(const float4*)(ebase + 4);
      uint4 pw;
      pw.x = pk2(e0.x, e0.y); pw.y = pk2(e0.z, e0.w);
      pw.z = pk2(e1.x, e1.y); pw.w = pk2(e1.z, e1.w);
      *(uint4*)&sFw[er * 72 + c * 8] = pw;

      if (lane < 16) {
        int j = jb + lane;
        const float* qr = (j < NN) ? q + ((size_t)(b * NN + j)) * 4
                                   : pq + ((size_t)(b * NP + (j - NN))) * 4;
        float4 qj = *(const float4*)qr;
        const float* xr = (j < NN) ? x + ((size_t)(b * NN + j)) * 3
                                   : px + ((size_t)(b * NP + (j - NN))) * 3;
        float xj0 = xr[0], xj1 = xr[1], xj2 = xr[2];
        float d0 = xi0 - xj0, d1 = xi1 - xj1, d2v = xi2 - xj2;
        float d2 = d0 * d0 + d1 * d1 + d2v * d2v;
        float qdot = fabsf(qi0 * qj.x + qi1 * qj.y + qi2 * qj.z + qi3 * qj.w);
        float ajw = qj.x, ajx = -qj.y, ajy = -qj.z, ajz = -qj.w;  // conj
        float t0 = 2.f * (ajy * d2v - ajz * d1);
        float t1 = 2.f * (ajz * d0 - ajx * d2v);
        float t2 = 2.f * (ajx * d1 - ajy * d0);
        float lx0 = d0 + ajw * t0 + (ajy * t2 - ajz * t1);
        float lx1 = d1 + ajw * t1 + (ajz * t0 - ajx * t2);
        float lx2 = d2v + ajw * t2 + (ajx * t1 - ajy * t0);
        float lqw = ajw * qi0 - ajx * qi1 - ajy * qi2 - ajz * qi3;
        float lqx = ajw * qi1 + ajx * qi0 + ajy * qi3 - ajz * qi2;
        float lqy = ajw * qi2 - ajx * qi3 + ajy * qi0 + ajz * qi1;
        float lqz = ajw * qi3 + ajx * qi2 - ajy * qi1 + ajz * qi0;
        float nn2 = qj.x * qj.x + qj.y * qj.y + qj.z * qj.z + qj.w * qj.w;
        float rn = 1.f / fmaxf(sqrtf(nn2), 1e-12f);
        nqw = qj.x * rn; nqx = qj.y * rn; nqy = qj.z * rn; nqz = qj.w * rn;
        uint4 g0, g1;
        g0.x = pk2(lx0, lx1); g0.y = pk2(lx2, lqw);
        g0.z = pk2(lqx, lqy); g0.w = pk2(lqz, d2);
        g1.x = pk2(qdot, 0.f); g1.y = 0; g1.z = 0; g1.w = 0;
        *(uint4*)&sFw[lane * 72 + 32] = g0;
        *(uint4*)&sFw[lane * 72 + 40] = g1;
      }
    }

    // ---- layer 1: acc = Hi + Hall[j] + F@W1 ----
    const float* hp = Hall + (size_t)(b * NJ + jb) * 64;
    f32x4 acc[4];
#pragma unroll
    for (int nt = 0; nt < 4; ++nt)
#pragma unroll
      for (int r = 0; r < 4; ++r)
        acc[nt][r] = HiF[nt] + hp[(quad * 4 + r) * 64 + nt * 16 + nl];
#pragma unroll
    for (int ks = 0; ks < 2; ++ks) {
      short8 af = *(const short8*)&sFw[nl * 72 + ks * 32 + quad * 8];
#pragma unroll
      for (int nt = 0; nt < 4; ++nt) {
        short8 bfr = *(const short8*)&sW1B[(nt * 16 + nl) * 72 + ks * 32 + quad * 8];
        acc[nt] = __builtin_amdgcn_mfma_f32_16x16x32_bf16(af, bfr, acc[nt], 0, 0, 0);
      }
    }
#pragma unroll
    for (int nt = 0; nt < 4; ++nt)
#pragma unroll
      for (int r = 0; r < 4; ++r)
        sTw[(quad * 4 + r) * 72 + nt * 16 + nl] = f2bf(fmaxf(acc[nt][r], 0.f));

    // ---- layer 2: m = a1@W2 + bm2 (W2 regs); mask j==i; msum ----
#pragma unroll
    for (int nt = 0; nt < 4; ++nt)
      acc[nt] = (f32x4){bm2F[nt], bm2F[nt], bm2F[nt], bm2F[nt]};
#pragma unroll
    for (int ks = 0; ks < 2; ++ks) {
      short8 af = *(const short8*)&sTw[nl * 72 + ks * 32 + quad * 8];
#pragma unroll
      for (int nt = 0; nt < 4; ++nt)
        acc[nt] = __builtin_amdgcn_mfma_f32_16x16x32_bf16(af, W2f[nt][ks], acc[nt], 0, 0, 0);
    }
#pragma unroll
    for (int nt = 0; nt < 4; ++nt)
#pragma unroll
      for (int r = 0; r < 4; ++r) {
        int row = quad * 4 + r;
        float v = acc[nt][r];
        if (jb + row == i) v = 0.f;
        msum[nt][r] += v;
        sTw[row * 72 + nt * 16 + nl] = f2bf(v);
      }

    // ---- dx layer 1: x1 = relu(m@Wx1 + bx1) (Wx1 from LDS) ----
#pragma unroll
    for (int nt = 0; nt < 4; ++nt)
      acc[nt] = (f32x4){bx1F[nt], bx1F[nt], bx1F[nt], bx1F[nt]};
#pragma unroll
    for (int ks = 0; ks < 2; ++ks) {
      short8 af = *(const short8*)&sTw[nl * 72 + ks * 32 + quad * 8];
#pragma unroll
      for (int nt = 0; nt < 4; ++nt) {
        short8 bfr = *(const short8*)&sWx1B[(nt * 16 + nl) * 72 + ks * 32 + quad * 8];
        acc[nt] = __builtin_amdgcn_mfma_f32_16x16x32_bf16(af, bfr, acc[nt], 0, 0, 0);
      }
    }
#pragma unroll
    for (int nt = 0; nt < 4; ++nt)
#pragma unroll
      for (int r = 0; r < 4; ++r)
        sTw[(quad * 4 + r) * 72 + nt * 16 + nl] = f2bf(fmaxf(acc[nt][r], 0.f));

    // ---- dx layer 2: dx = x1@Wx2 + bx2 (cols 0..2) ----
    f32x4 dacc = (f32x4){bx2F, bx2F, bx2F, bx2F};
#pragma unroll
    for (int ks = 0; ks < 2; ++ks) {
      short8 af = *(const short8*)&sTw[nl * 72 + ks * 32 + quad * 8];
      dacc = __builtin_amdgcn_mfma_f32_16x16x32_bf16(af, Wx2f[ks], dacc, 0, 0, 0);
    }
    if (nl < 3) {
#pragma unroll
      for (int r = 0; r < 4; ++r) sDxT[wid][quad * 4 + r][nl] = dacc[r];
    }
    if (lane < 16) {
      int j = jb + lane;
      if (j != i) {
        float dxc0 = sDxT[wid][lane][0];
        float dxc1 = sDxT[wid][lane][1];
        float dxc2 = sDxT[wid][lane][2];
        float rt0 = 2.f * (nqy * dxc2 - nqz * dxc1);
        float rt1 = 2.f * (nqz * dxc0 - nqx * dxc2);
        float rt2 = 2.f * (nqx * dxc1 - nqy * dxc0);
        dxs0 += dxc0 + nqw * rt0 + (nqy * rt2 - nqz * rt1);
        dxs1 += dxc1 + nqw * rt1 + (nqz * rt0 - nqx * rt2);
        dxs2 += dxc2 + nqw * rt2 + (nqx * rt1 - nqy * rt0);
      }
    }
  }

  // ---- reductions + partial writes ----
#pragma unroll
  for (int nt = 0; nt < 4; ++nt) {
    float s = msum[nt][0] + msum[nt][1] + msum[nt][2] + msum[nt][3];
    s += __shfl_xor(s, 16);
    s += __shfl_xor(s, 32);
    if (lane < 16) sMsum[wid][nt * 16 + lane] = s;
  }
  {
    float a = dxs0, bb = dxs1, cc = dxs2;
#pragma unroll
    for (int off = 1; off < 16; off <<= 1) {
      a += __shfl_xor(a, off);
      bb += __shfl_xor(bb, off);
      cc += __shfl_xor(cc, off);
    }
    if (lane == 0) { sDxS[wid][0] = a; sDxS[wid][1] = bb; sDxS[wid][2] = cc; }
  }
  __syncthreads();
  if (wid == 0) {
    float ms = sMsum[0][lane] + sMsum[1][lane] + sMsum[2][lane] + sMsum[3][lane];
    pm[(size_t)node * 256 + part * 64 + lane] = ms;
  } else if (wid == 1 && lane < 3) {
    float xs = sDxS[0][lane] + sDxS[1][lane] + sDxS[2][lane] + sDxS[3][lane];
    pdx[(size_t)node * 16 + part * 4 + lane] = xs;
  }
}

// ---------------------------------------------------------------------------
// K3: per-node epilogues. grid = 512, 256 threads (4 waves, one per output).
// ---------------------------------------------------------------------------
__global__ void __launch_bounds__(256)
k3_epilogue(const float* __restrict__ q, const float* __restrict__ x,
            const float* __restrict__ h,
            const float* __restrict__ Wf1, const float* __restrict__ bf1,
            const float* __restrict__ Wf2, const float* __restrict__ bf2_,
            const float* __restrict__ Wq1, const float* __restrict__ bq1,
            const float* __restrict__ Wq2, const float* __restrict__ bq2,
            const float* __restrict__ Wt1, const float* __restrict__ bt1,
            const float* __restrict__ Wt2, const float* __restrict__ bt2,
            const float* __restrict__ pm, const float* __restrict__ pdx,
            float* __restrict__ out)
{
  __shared__ float sHi64[64], sMs[64], sPh[3][64];
  const size_t node = blockIdx.x;
  const int tid = threadIdx.x;
  const int wid = tid >> 6;
  const int lane = tid & 63;
  if (tid < 64) sHi64[tid] = h[node * 64 + tid];
  else if (tid < 128) {
    int c = tid - 64;
    sMs[c] = pm[node * 256 + c] + pm[node * 256 + 64 + c] +
             pm[node * 256 + 128 + c] + pm[node * 256 + 192 + c];
  }
  __syncthreads();

  if (wid == 0) {
    float f1a = bf1[lane], f1b = 0.f;
#pragma unroll 8
    for (int k = 0; k < 64; ++k) {
      f1a += sHi64[k] * Wf1[k * 64 + lane];
      f1b += sMs[k] * Wf1[(64 + k) * 64 + lane];
    }
    float f1 = fmaxf(f1a + f1b, 0.f);
    sPh[0][lane] = f1;
    float oacc = bf2_[lane];
#pragma unroll 8
    for (int k = 0; k < 64; ++k) oacc += sPh[0][k] * Wf2[k * 64 + lane];
    out[OFF_O + node * 64 + lane] = oacc;
  } else if (wid == 1) {
    float a = bq1[lane];
#pragma unroll 8
    for (int k = 0; k < 64; ++k) a += sMs[k] * Wq1[k * 64 + lane];
    a = fmaxf(a, 0.f);
    float p0 = a * Wq2[lane * 4 + 0];
    float p1 = a * Wq2[lane * 4 + 1];
    float p2 = a * Wq2[lane * 4 + 2];
    float p3 = a * Wq2[lane * 4 + 3];
#pragma unroll
    for (int off = 32; off >= 1; off >>= 1) {
      p0 += __shfl_xor(p0, off);
      p1 += __shfl_xor(p1, off);
      p2 += __shfl_xor(p2, off);
      p3 += __shfl_xor(p3, off);
    }
    float dq0 = p0 + bq2[0], dq1 = p1 + bq2[1];
    float dq2 = p2 + bq2[2], dq3 = p3 + bq2[3];
    float n = fmaxf(sqrtf(dq0 * dq0 + dq1 * dq1 + dq2 * dq2 + dq3 * dq3), 1e-12f);
    dq0 /= n; dq1 /= n; dq2 /= n; dq3 /= n;
    const float* qr = q + node * 4;
    float qi0 = qr[0], qi1 = qr[1], qi2 = qr[2], qi3 = qr[3];
    float uw = qi0 * dq0 - qi1 * dq1 - qi2 * dq2 - qi3 * dq3;
    float ux = qi0 * dq1 + qi1 * dq0 + qi2 * dq3 - qi3 * dq2;
    float uy = qi0 * dq2 - qi1 * dq3 + qi2 * dq0 + qi3 * dq1;
    float uz = qi0 * dq3 + qi1 * dq2 - qi2 * dq1 + qi3 * dq0;
    float n2 = fmaxf(sqrtf(uw * uw + ux * ux + uy * uy + uz * uz), 1e-12f);
    if (lane == 0) {
      float* po = out + OFF_Q + node * 4;
      po[0] = uw / n2; po[1] = ux / n2; po[2] = uy / n2; po[3] = uz / n2;
    }
  } else if (wid == 2) {
    float a = bt1[lane];
#pragma unroll 8
    for (int k = 0; k < 64; ++k) a += sMs[k] * Wt1[k * 64 + lane];
    a = fmaxf(a, 0.f);
    sPh[2][lane] = a;
    if (lane < 14) {
      float v = bt2[lane];
#pragma unroll 8
      for (int k = 0; k < 64; ++k) v += sPh[2][k] * Wt2[k * 14 + lane];
      float pv = __shfl_xor(v, 1);
      float nrm = fmaxf(sqrtf(v * v + pv * pv), 1e-12f);
      out[OFF_T + node * 14 + lane] = v / nrm;
    }
  } else {
    if (lane < 3) {
      float xs = pdx[node * 16 + lane] + pdx[node * 16 + 4 + lane] +
                 pdx[node * 16 + 8 + lane] + pdx[node * 16 + 12 + lane];
      out[OFF_X + node * 3 + lane] = x[node * 3 + lane] + xs / 639.0f;
    }
  }
}

extern "C" void kernel_launch(void* const* d_in, const int* in_sizes, int n_in,
                              void* d_out, int out_size, void* d_ws, size_t ws_size,
                              hipStream_t stream) {
  const float* q   = (const float*)d_in[0];
  const float* x   = (const float*)d_in[1];
  const float* h   = (const float*)d_in[3];
  const float* e   = (const float*)d_in[4];
  const float* pq  = (const float*)d_in[6];
  const float* px  = (const float*)d_in[7];
  const float* pe  = (const float*)d_in[8];
  const float* ph  = (const float*)d_in[9];
  const float* Wm1 = (const float*)d_in[11];
  const float* bm1 = (const float*)d_in[12];
  const float* Wm2 = (const float*)d_in[13];
  const float* bm2 = (const float*)d_in[14];
  const float* Wf1 = (const float*)d_in[15];
  const float* bf1 = (const float*)d_in[16];
  const float* Wf2 = (const float*)d_in[17];
  const float* bf2_ = (const float*)d_in[18];
  const float* Wx1 = (const float*)d_in[19];
  const float* bx1 = (const float*)d_in[20];
  const float* Wx2 = (const float*)d_in[21];
  const float* bx2 = (const float*)d_in[22];
  const float* Wq1 = (const float*)d_in[23];
  const float* bq1 = (const float*)d_in[24];
  const float* Wq2 = (const float*)d_in[25];
  const float* bq2 = (const float*)d_in[26];
  const float* Wt1 = (const float*)d_in[27];
  const float* bt1 = (const float*)d_in[28];
  const float* Wt2 = (const float*)d_in[29];
  const float* bt2 = (const float*)d_in[30];

  float* ws = (float*)d_ws;
  float* Hall = ws + WS_HALL;
  float* Hi   = ws + WS_HI;
  float* pm   = ws + WS_PM;
  float* pdx  = ws + WS_PDX;

  k1_precompute<<<192, 256, 0, stream>>>(h, ph, Wm1, bm1, Hall, Hi);

  k2_edges<<<NB * NN * 4, 256, 0, stream>>>(
      q, x, e, pe, pq, px, Wm1, Wm2, bm2, Wx1, bx1, Wx2, bx2,
      Hall, Hi, pm, pdx);

  k3_epilogue<<<NB * NN, 256, 0, stream>>>(
      q, x, h, Wf1, bf1, Wf2, bf2_, Wq1, bq1, Wq2, bq2,
      Wt1, bt1, Wt2, bt2, pm, pdx, (float*)d_out);
}

// Round 10
// 199.643 us; speedup vs baseline: 1.2651x; 1.1055x over previous
//
#include <hip/hip_runtime.h>
#include <stdint.h>

#define NB 4
#define NN 128
#define NP 512
#define NJ 640
#define HD 64
#define ED 32

typedef unsigned short u16;
typedef __attribute__((ext_vector_type(8))) short short8;
typedef __attribute__((ext_vector_type(4))) float f32x4;

// out element offsets (f32): upd_q[2048], upd_x[1536], tor[7168], o[32768]
#define OFF_Q 0
#define OFF_X 2048
#define OFF_T 3584
#define OFF_O 10752

// d_ws float offsets
#define WS_HALL 0         // 4*640*64 = 163840
#define WS_HI   163840    // 512*64   = 32768
#define WS_PM   196608    // 512*2*64 = 65536  (Asum partials)
#define WS_PDX  262144    // 512*2*4  = 4096
#define WS_WC   266240    // 64*64    = 4096   (Wc = Wm2@Wx1)
#define WS_BC   270336    // 64              (bc = bm2@Wx1+bx1)

__device__ __forceinline__ u16 f2bf(float f) {
  union { float f; uint32_t i; } v; v.f = f;
  uint32_t x = v.i;
  return (u16)((x + 0x7FFFu + ((x >> 16) & 1u)) >> 16);
}
__device__ __forceinline__ uint32_t pk2(float a, float b) {
  return (uint32_t)f2bf(a) | ((uint32_t)f2bf(b) << 16);
}

// ---------------------------------------------------------------------------
// K1: blocks 0..159: Hall = h_all@Wm1[64:128] (16 rows each)
//     blocks 160..191: Hi = h@Wm1[0:64]+bm1
//     block 192: Wc = Wm2@Wx1, bc = bm2@Wx1+bx1
// ---------------------------------------------------------------------------
__global__ void __launch_bounds__(256)
k1_precompute(const float* __restrict__ h, const float* __restrict__ ph,
              const float* __restrict__ Wm1, const float* __restrict__ bm1,
              const float* __restrict__ Wm2, const float* __restrict__ bm2,
              const float* __restrict__ Wx1, const float* __restrict__ bx1,
              float* __restrict__ Hall, float* __restrict__ Hi,
              float* __restrict__ Wc, float* __restrict__ bc)
{
  __shared__ float sW[64 * 64];
  __shared__ float sW2[64 * 64];
  const int blk = blockIdx.x;
  const int tid = threadIdx.x;
  if (blk < 192) {
    const bool isHi = blk >= 160;
    const int wofs = isHi ? 0 : 64;
    for (int idx = tid; idx < 4096; idx += 256)
      sW[idx] = Wm1[(size_t)(wofs + (idx >> 6)) * 64 + (idx & 63)];
    __syncthreads();
    const int lane = tid & 63;
    const int wid = tid >> 6;
    const int base = (isHi ? (blk - 160) : blk) * 16 + wid * 4;
    const float* hr[4];
#pragma unroll
    for (int u = 0; u < 4; ++u) {
      int rr = base + u;
      if (isHi) hr[u] = h + (size_t)rr * 64;
      else {
        int bb = rr / NJ, j = rr % NJ;
        hr[u] = (j < NN) ? h + (size_t)(bb * NN + j) * 64
                         : ph + (size_t)(bb * NP + (j - NN)) * 64;
      }
    }
    float a0 = isHi ? bm1[lane] : 0.f, a1 = a0, a2 = a0, a3 = a0;
#pragma unroll 8
    for (int k = 0; k < 64; ++k) {
      float w = sW[k * 64 + lane];
      a0 += hr[0][k] * w; a1 += hr[1][k] * w;
      a2 += hr[2][k] * w; a3 += hr[3][k] * w;
    }
    float* dst = isHi ? Hi : Hall;
    dst[(size_t)(base + 0) * 64 + lane] = a0;
    dst[(size_t)(base + 1) * 64 + lane] = a1;
    dst[(size_t)(base + 2) * 64 + lane] = a2;
    dst[(size_t)(base + 3) * 64 + lane] = a3;
  } else {
    // Wc = Wm2 @ Wx1 ; bc = bm2 @ Wx1 + bx1
    for (int idx = tid; idx < 4096; idx += 256) {
      sW[idx] = Wx1[idx];
      sW2[idx] = Wm2[idx];
    }
    __syncthreads();
    for (int idx = tid; idx < 4096; idx += 256) {
      int t = idx >> 6, n3 = idx & 63;
      float acc = 0.f;
#pragma unroll 8
      for (int n2 = 0; n2 < 64; ++n2)
        acc += sW2[t * 64 + n2] * sW[n2 * 64 + n3];
      Wc[idx] = acc;
    }
    if (tid < 64) {
      float a = bx1[tid];
#pragma unroll 8
      for (int n2 = 0; n2 < 64; ++n2) a += bm2[n2] * sW[n2 * 64 + tid];
      bc[tid] = a;
    }
  }
}

// ---------------------------------------------------------------------------
// K2: edge loop. grid = 1024 (node x 2 parts, 20 tiles each), 256 threads,
// 4 waves x 5 tiles. F layout (bf16, 72-short rows): k0..31=e, k32..40=geo.
// Per tile: F@W1 -> a1 (relu, mask, Asum+=) -> a1@Wc -> x1 (relu) -> x1@Wx2.
// Layer-2 (Wm2) folded out of the loop: msum reconstructed in K3 from Asum.
// NO min-waves bound (forced splits spilled in rounds 4/6/7/8).
// ---------------------------------------------------------------------------
__global__ void __launch_bounds__(256)
k2_edges(const float* __restrict__ q, const float* __restrict__ x,
         const float* __restrict__ e, const float* __restrict__ pe,
         const float* __restrict__ pq, const float* __restrict__ px,
         const float* __restrict__ Wm1, const float* __restrict__ Wx2,
         const float* __restrict__ bx2,
         const float* __restrict__ Hall, const float* __restrict__ Hi,
         const float* __restrict__ Wc, const float* __restrict__ bc,
         float* __restrict__ pm, float* __restrict__ pdx)
{
  __shared__ u16 sW1B[64 * 72];    // W1 (K=64 compact), [n][k]
  __shared__ u16 sWcB[64 * 72];    // Wc, [n][k]
  __shared__ u16 sF[4][16 * 72];   // per-wave feature tile
  __shared__ u16 sT[4][16 * 72];   // per-wave transform buffer
  __shared__ float sDxT[4][16][4];
  __shared__ float sAs[4][64];
  __shared__ float sDxS[4][4];

  const int node = blockIdx.x >> 1;
  const int part = blockIdx.x & 1;
  const int b = node >> 7;
  const int i = node & 127;
  const int tid = threadIdx.x;
  const int wid = tid >> 6;
  const int lane = tid & 63;
  const int nl = lane & 15;
  const int quad = lane >> 4;

  u16* sFw = sF[wid];
  u16* sTw = sT[wid];

  // stage W1 / Wc to LDS (bf16, [n][k])
  for (int idx = tid; idx < 64 * 64; idx += 256) {
    int n = idx >> 6, k = idx & 63;
    int row = (k < 32) ? (128 + k) : ((k < 41) ? (160 + (k - 32)) : -1);
    sW1B[n * 72 + k] = (row < 0) ? (u16)0 : f2bf(Wm1[(size_t)row * 64 + n]);
    sWcB[n * 72 + k] = f2bf(Wc[(size_t)k * 64 + n]);
  }
  // zero own F tile (pad cols 41..63 stay zero; live cols rewritten per tile)
  for (int idx = lane; idx < 16 * 72 / 2; idx += 64) ((uint32_t*)sFw)[idx] = 0;

  const float* qr0 = q + (size_t)node * 4;
  const float qi0 = qr0[0], qi1 = qr0[1], qi2 = qr0[2], qi3 = qr0[3];
  const float* xr0 = x + (size_t)node * 3;
  const float xi0 = xr0[0], xi1 = xr0[1], xi2 = xr0[2];

  // register B-frags: Wx2 only (8 VGPR)
  short8 Wx2f[2];
#pragma unroll
  for (int ks = 0; ks < 2; ++ks) {
    short8 v;
#pragma unroll
    for (int jj = 0; jj < 8; ++jj) {
      int k = ks * 32 + quad * 8 + jj;
      v[jj] = (nl < 3) ? (short)f2bf(Wx2[(size_t)k * 3 + nl]) : (short)0;
    }
    Wx2f[ks] = v;
  }

  float HiF[4], bcF[4];
#pragma unroll
  for (int nt = 0; nt < 4; ++nt) {
    HiF[nt] = Hi[(size_t)node * 64 + nt * 16 + nl];
    bcF[nt] = bc[nt * 16 + nl];
  }
  const float bx2F = (nl < 3) ? bx2[nl] : 0.f;

  __syncthreads();  // W1/Wc staged

  f32x4 Asum[4];
#pragma unroll
  for (int nt = 0; nt < 4; ++nt) Asum[nt] = (f32x4){0.f, 0.f, 0.f, 0.f};
  float dxs0 = 0.f, dxs1 = 0.f, dxs2 = 0.f;
  float nqw = 0.f, nqx = 0.f, nqy = 0.f, nqz = 0.f;

  for (int t = wid; t < 20; t += 4) {
    const int jb = (part * 20 + t) * 16;

    // ---- Hall prefetch (overlaps with F build + L1 MFMAs) ----
    const float* hp = Hall + (size_t)(b * NJ + jb) * 64;
    float hallv[4][4];
#pragma unroll
    for (int nt = 0; nt < 4; ++nt)
#pragma unroll
      for (int r = 0; r < 4; ++r)
        hallv[nt][r] = hp[(quad * 4 + r) * 64 + nt * 16 + nl];

    // ---- build F (wave-private LDS, no block barrier) ----
    {
      int er = lane >> 2, c = lane & 3;
      int jr = jb + er;
      const float* ebase = (jr < NN)
          ? e + (((size_t)node * NN) + jr) * ED + c * 8
          : pe + (((size_t)node * NP) + (jr - NN)) * ED + c * 8;
      float4 e0 = *(const float4*)ebase;
      float4 e1 = *(const float4*)(ebase + 4);
      uint4 pw;
      pw.x = pk2(e0.x, e0.y); pw.y = pk2(e0.z, e0.w);
      pw.z = pk2(e1.x, e1.y); pw.w = pk2(e1.z, e1.w);
      *(uint4*)&sFw[er * 72 + c * 8] = pw;

      if (lane < 16) {
        int j = jb + lane;
        const float* qr = (j < NN) ? q + ((size_t)(b * NN + j)) * 4
                                   : pq + ((size_t)(b * NP + (j - NN))) * 4;
        float4 qj = *(const float4*)qr;
        const float* xr = (j < NN) ? x + ((size_t)(b * NN + j)) * 3
                                   : px + ((size_t)(b * NP + (j - NN))) * 3;
        float xj0 = xr[0], xj1 = xr[1], xj2 = xr[2];
        float d0 = xi0 - xj0, d1 = xi1 - xj1, d2v = xi2 - xj2;
        float d2 = d0 * d0 + d1 * d1 + d2v * d2v;
        float qdot = fabsf(qi0 * qj.x + qi1 * qj.y + qi2 * qj.z + qi3 * qj.w);
        float ajw = qj.x, ajx = -qj.y, ajy = -qj.z, ajz = -qj.w;  // conj
        float t0 = 2.f * (ajy * d2v - ajz * d1);
        float t1 = 2.f * (ajz * d0 - ajx * d2v);
        float t2 = 2.f * (ajx * d1 - ajy * d0);
        float lx0 = d0 + ajw * t0 + (ajy * t2 - ajz * t1);
        float lx1 = d1 + ajw * t1 + (ajz * t0 - ajx * t2);
        float lx2 = d2v + ajw * t2 + (ajx * t1 - ajy * t0);
        float lqw = ajw * qi0 - ajx * qi1 - ajy * qi2 - ajz * qi3;
        float lqx = ajw * qi1 + ajx * qi0 + ajy * qi3 - ajz * qi2;
        float lqy = ajw * qi2 - ajx * qi3 + ajy * qi0 + ajz * qi1;
        float lqz = ajw * qi3 + ajx * qi2 - ajy * qi1 + ajz * qi0;
        float nn2 = qj.x * qj.x + qj.y * qj.y + qj.z * qj.z + qj.w * qj.w;
        float rn = 1.f / fmaxf(sqrtf(nn2), 1e-12f);
        nqw = qj.x * rn; nqx = qj.y * rn; nqy = qj.z * rn; nqz = qj.w * rn;
        uint4 g0, g1;
        g0.x = pk2(lx0, lx1); g0.y = pk2(lx2, lqw);
        g0.z = pk2(lqx, lqy); g0.w = pk2(lqz, d2);
        g1.x = pk2(qdot, 0.f); g1.y = 0; g1.z = 0; g1.w = 0;
        *(uint4*)&sFw[lane * 72 + 32] = g0;
        *(uint4*)&sFw[lane * 72 + 40] = g1;
      }
    }

    // ---- layer 1: a1 = relu(F@W1 + Hi + Hall), mask j==i, Asum += a1 ----
    f32x4 acc[4];
#pragma unroll
    for (int nt = 0; nt < 4; ++nt) acc[nt] = (f32x4){0.f, 0.f, 0.f, 0.f};
#pragma unroll
    for (int ks = 0; ks < 2; ++ks) {
      short8 af = *(const short8*)&sFw[nl * 72 + ks * 32 + quad * 8];
#pragma unroll
      for (int nt = 0; nt < 4; ++nt) {
        short8 bfr = *(const short8*)&sW1B[(nt * 16 + nl) * 72 + ks * 32 + quad * 8];
        acc[nt] = __builtin_amdgcn_mfma_f32_16x16x32_bf16(af, bfr, acc[nt], 0, 0, 0);
      }
    }
#pragma unroll
    for (int nt = 0; nt < 4; ++nt)
#pragma unroll
      for (int r = 0; r < 4; ++r) {
        int row = quad * 4 + r;
        float v = fmaxf(acc[nt][r] + HiF[nt] + hallv[nt][r], 0.f);
        if (jb + row == i) v = 0.f;
        Asum[nt][r] += v;
        sTw[row * 72 + nt * 16 + nl] = f2bf(v);
      }

    // ---- x1 = relu(a1@Wc + bc) (Wc from LDS) ----
#pragma unroll
    for (int nt = 0; nt < 4; ++nt)
      acc[nt] = (f32x4){bcF[nt], bcF[nt], bcF[nt], bcF[nt]};
#pragma unroll
    for (int ks = 0; ks < 2; ++ks) {
      short8 af = *(const short8*)&sTw[nl * 72 + ks * 32 + quad * 8];
#pragma unroll
      for (int nt = 0; nt < 4; ++nt) {
        short8 bfr = *(const short8*)&sWcB[(nt * 16 + nl) * 72 + ks * 32 + quad * 8];
        acc[nt] = __builtin_amdgcn_mfma_f32_16x16x32_bf16(af, bfr, acc[nt], 0, 0, 0);
      }
    }
#pragma unroll
    for (int nt = 0; nt < 4; ++nt)
#pragma unroll
      for (int r = 0; r < 4; ++r)
        sTw[(quad * 4 + r) * 72 + nt * 16 + nl] = f2bf(fmaxf(acc[nt][r], 0.f));

    // ---- dx = x1@Wx2 + bx2 (cols 0..2) ----
    f32x4 dacc = (f32x4){bx2F, bx2F, bx2F, bx2F};
#pragma unroll
    for (int ks = 0; ks < 2; ++ks) {
      short8 af = *(const short8*)&sTw[nl * 72 + ks * 32 + quad * 8];
      dacc = __builtin_amdgcn_mfma_f32_16x16x32_bf16(af, Wx2f[ks], dacc, 0, 0, 0);
    }
    if (nl < 3) {
#pragma unroll
      for (int r = 0; r < 4; ++r) sDxT[wid][quad * 4 + r][nl] = dacc[r];
    }
    if (lane < 16) {
      int j = jb + lane;
      if (j != i) {
        float dxc0 = sDxT[wid][lane][0];
        float dxc1 = sDxT[wid][lane][1];
        float dxc2 = sDxT[wid][lane][2];
        float rt0 = 2.f * (nqy * dxc2 - nqz * dxc1);
        float rt1 = 2.f * (nqz * dxc0 - nqx * dxc2);
        float rt2 = 2.f * (nqx * dxc1 - nqy * dxc0);
        dxs0 += dxc0 + nqw * rt0 + (nqy * rt2 - nqz * rt1);
        dxs1 += dxc1 + nqw * rt1 + (nqz * rt0 - nqx * rt2);
        dxs2 += dxc2 + nqw * rt2 + (nqx * rt1 - nqy * rt0);
      }
    }
  }

  // ---- reductions + partial writes ----
#pragma unroll
  for (int nt = 0; nt < 4; ++nt) {
    float s = Asum[nt][0] + Asum[nt][1] + Asum[nt][2] + Asum[nt][3];
    s += __shfl_xor(s, 16);
    s += __shfl_xor(s, 32);
    if (lane < 16) sAs[wid][nt * 16 + lane] = s;
  }
  {
    float a = dxs0, bb = dxs1, cc = dxs2;
#pragma unroll
    for (int off = 1; off < 16; off <<= 1) {
      a += __shfl_xor(a, off);
      bb += __shfl_xor(bb, off);
      cc += __shfl_xor(cc, off);
    }
    if (lane == 0) { sDxS[wid][0] = a; sDxS[wid][1] = bb; sDxS[wid][2] = cc; }
  }
  __syncthreads();
  if (wid == 0) {
    float ms = sAs[0][lane] + sAs[1][lane] + sAs[2][lane] + sAs[3][lane];
    pm[(size_t)node * 128 + part * 64 + lane] = ms;
  } else if (wid == 1 && lane < 3) {
    float xs = sDxS[0][lane] + sDxS[1][lane] + sDxS[2][lane] + sDxS[3][lane];
    pdx[(size_t)node * 8 + part * 4 + lane] = xs;
  }
}

// ---------------------------------------------------------------------------
// K3: per-node: msum = Asum@Wm2 + 639*bm2 (f32), then the four epilogues.
// grid = 512, 256 threads.
// ---------------------------------------------------------------------------
__global__ void __launch_bounds__(256)
k3_epilogue(const float* __restrict__ q, const float* __restrict__ x,
            const float* __restrict__ h,
            const float* __restrict__ Wm2, const float* __restrict__ bm2,
            const float* __restrict__ Wf1, const float* __restrict__ bf1,
            const float* __restrict__ Wf2, const float* __restrict__ bf2_,
            const float* __restrict__ Wq1, const float* __restrict__ bq1,
            const float* __restrict__ Wq2, const float* __restrict__ bq2,
            const float* __restrict__ Wt1, const float* __restrict__ bt1,
            const float* __restrict__ Wt2, const float* __restrict__ bt2,
            const float* __restrict__ pm, const float* __restrict__ pdx,
            float* __restrict__ out)
{
  __shared__ float sHi64[64], sAs[64], sMs[64], sPh[3][64];
  const size_t node = blockIdx.x;
  const int tid = threadIdx.x;
  const int wid = tid >> 6;
  const int lane = tid & 63;
  if (tid < 64) sAs[tid] = pm[node * 128 + tid] + pm[node * 128 + 64 + tid];
  else if (tid < 128) sHi64[tid - 64] = h[node * 64 + (tid - 64)];
  __syncthreads();
  if (tid < 64) {
    float acc = 639.0f * bm2[tid];
#pragma unroll 8
    for (int k = 0; k < 64; ++k) acc += sAs[k] * Wm2[k * 64 + tid];
    sMs[tid] = acc;
  }
  __syncthreads();

  if (wid == 0) {
    float f1a = bf1[lane], f1b = 0.f;
#pragma unroll 8
    for (int k = 0; k < 64; ++k) {
      f1a += sHi64[k] * Wf1[k * 64 + lane];
      f1b += sMs[k] * Wf1[(64 + k) * 64 + lane];
    }
    float f1 = fmaxf(f1a + f1b, 0.f);
    sPh[0][lane] = f1;
    float oacc = bf2_[lane];
#pragma unroll 8
    for (int k = 0; k < 64; ++k) oacc += sPh[0][k] * Wf2[k * 64 + lane];
    out[OFF_O + node * 64 + lane] = oacc;
  } else if (wid == 1) {
    float a = bq1[lane];
#pragma unroll 8
    for (int k = 0; k < 64; ++k) a += sMs[k] * Wq1[k * 64 + lane];
    a = fmaxf(a, 0.f);
    float p0 = a * Wq2[lane * 4 + 0];
    float p1 = a * Wq2[lane * 4 + 1];
    float p2 = a * Wq2[lane * 4 + 2];
    float p3 = a * Wq2[lane * 4 + 3];
#pragma unroll
    for (int off = 32; off >= 1; off >>= 1) {
      p0 += __shfl_xor(p0, off);
      p1 += __shfl_xor(p1, off);
      p2 += __shfl_xor(p2, off);
      p3 += __shfl_xor(p3, off);
    }
    float dq0 = p0 + bq2[0], dq1 = p1 + bq2[1];
    float dq2 = p2 + bq2[2], dq3 = p3 + bq2[3];
    float n = fmaxf(sqrtf(dq0 * dq0 + dq1 * dq1 + dq2 * dq2 + dq3 * dq3), 1e-12f);
    dq0 /= n; dq1 /= n; dq2 /= n; dq3 /= n;
    const float* qr = q + node * 4;
    float qi0 = qr[0], qi1 = qr[1], qi2 = qr[2], qi3 = qr[3];
    float uw = qi0 * dq0 - qi1 * dq1 - qi2 * dq2 - qi3 * dq3;
    float ux = qi0 * dq1 + qi1 * dq0 + qi2 * dq3 - qi3 * dq2;
    float uy = qi0 * dq2 - qi1 * dq3 + qi2 * dq0 + qi3 * dq1;
    float uz = qi0 * dq3 + qi1 * dq2 - qi2 * dq1 + qi3 * dq0;
    float n2 = fmaxf(sqrtf(uw * uw + ux * ux + uy * uy + uz * uz), 1e-12f);
    if (lane == 0) {
      float* po = out + OFF_Q + node * 4;
      po[0] = uw / n2; po[1] = ux / n2; po[2] = uy / n2; po[3] = uz / n2;
    }
  } else if (wid == 2) {
    float a = bt1[lane];
#pragma unroll 8
    for (int k = 0; k < 64; ++k) a += sMs[k] * Wt1[k * 64 + lane];
    a = fmaxf(a, 0.f);
    sPh[2][lane] = a;
    if (lane < 14) {
      float v = bt2[lane];
#pragma unroll 8
      for (int k = 0; k < 64; ++k) v += sPh[2][k] * Wt2[k * 14 + lane];
      float pv = __shfl_xor(v, 1);
      float nrm = fmaxf(sqrtf(v * v + pv * pv), 1e-12f);
      out[OFF_T + node * 14 + lane] = v / nrm;
    }
  } else {
    if (lane < 3) {
      float xs = pdx[node * 8 + lane] + pdx[node * 8 + 4 + lane];
      out[OFF_X + node * 3 + lane] = x[node * 3 + lane] + xs / 639.0f;
    }
  }
}

extern "C" void kernel_launch(void* const* d_in, const int* in_sizes, int n_in,
                              void* d_out, int out_size, void* d_ws, size_t ws_size,
                              hipStream_t stream) {
  const float* q   = (const float*)d_in[0];
  const float* x   = (const float*)d_in[1];
  const float* h   = (const float*)d_in[3];
  const float* e   = (const float*)d_in[4];
  const float* pq  = (const float*)d_in[6];
  const float* px  = (const float*)d_in[7];
  const float* pe  = (const float*)d_in[8];
  const float* ph  = (const float*)d_in[9];
  const float* Wm1 = (const float*)d_in[11];
  const float* bm1 = (const float*)d_in[12];
  const float* Wm2 = (const float*)d_in[13];
  const float* bm2 = (const float*)d_in[14];
  const float* Wf1 = (const float*)d_in[15];
  const float* bf1 = (const float*)d_in[16];
  const float* Wf2 = (const float*)d_in[17];
  const float* bf2_ = (const float*)d_in[18];
  const float* Wx1 = (const float*)d_in[19];
  const float* bx1 = (const float*)d_in[20];
  const float* Wx2 = (const float*)d_in[21];
  const float* bx2 = (const float*)d_in[22];
  const float* Wq1 = (const float*)d_in[23];
  const float* bq1 = (const float*)d_in[24];
  const float* Wq2 = (const float*)d_in[25];
  const float* bq2 = (const float*)d_in[26];
  const float* Wt1 = (const float*)d_in[27];
  const float* bt1 = (const float*)d_in[28];
  const float* Wt2 = (const float*)d_in[29];
  const float* bt2 = (const float*)d_in[30];

  float* ws = (float*)d_ws;
  float* Hall = ws + WS_HALL;
  float* Hi   = ws + WS_HI;
  float* pm   = ws + WS_PM;
  float* pdx  = ws + WS_PDX;
  float* Wc   = ws + WS_WC;
  float* bc   = ws + WS_BC;

  k1_precompute<<<193, 256, 0, stream>>>(h, ph, Wm1, bm1, Wm2, bm2, Wx1, bx1,
                                         Hall, Hi, Wc, bc);

  k2_edges<<<NB * NN * 2, 256, 0, stream>>>(
      q, x, e, pe, pq, px, Wm1, Wx2, bx2, Hall, Hi, Wc, bc, pm, pdx);

  k3_epilogue<<<NB * NN, 256, 0, stream>>>(
      q, x, h, Wm2, bm2, Wf1, bf1, Wf2, bf2_, Wq1, bq1, Wq2, bq2,
      Wt1, bt1, Wt2, bt2, pm, pdx, (float*)d_out);
}